// Round 8
// baseline (1480.415 us; speedup 1.0000x reference)
//
#include <hip/hip_runtime.h>
#include <math.h>

// Problem constants
#define BB   32
#define NN   200
#define SS   192
#define FIN  8
#define HH   64
#define PP   48
#define FNN  4
#define KK   10
#define NBLK 3
#define EPSF 1e-5f
#define SH   (SS*HH)               // 12288
#define XSZ  ((size_t)BB*NN*SS*HH) // 78,643,200 elements
#define ROWS (BB*NN)               // 6400
#define NPAD 208                   // node dim padded
#define KPAD 224                   // node contraction padded
#define XP2  232                   // xT LDS pitch (>= KPAD! 16B-aligned, 2-way banks)
#define ZPITCH 72                  // z LDS pitch (16B-aligned, 2-way-max banks)
// union LDS: xT = 128 rows x XP2 (29696 u16) <= z = 416 rows x ZPITCH (29952 u16)
#define SM2  (416*ZPITCH)          // 29952 u16 = 59904 B

typedef __attribute__((ext_vector_type(8))) short bf16x8;
typedef __attribute__((ext_vector_type(4))) float f32x4;

// bf16 <-> f32 helpers on raw ushort storage
__device__ __forceinline__ float bf2f(unsigned short u) {
    union { unsigned int i; float f; } v; v.i = ((unsigned int)u) << 16; return v.f;
}
__device__ __forceinline__ unsigned short f2bf(float f) {
    union { float f; unsigned int i; } v; v.f = f;
    unsigned int r = v.i + 0x7FFFu + ((v.i >> 16) & 1u);   // round-nearest-even
    return (unsigned short)(r >> 16);
}

__device__ __forceinline__ float wave_sum(float v) {
    #pragma unroll
    for (int off = 32; off > 0; off >>= 1) v += __shfl_xor(v, off, 64);
    return v;
}
__device__ __forceinline__ float wave_max(float v) {
    #pragma unroll
    for (int off = 32; off > 0; off >>= 1) v = fmaxf(v, __shfl_xor(v, off, 64));
    return v;
}

// ---------------------------------------------------------------------------
// Adjacency: la = relu(E E^T); top-K mask; softmax; blend with adj; diag=1;
// store un-normalized row + d_r. One wave per row.
// ---------------------------------------------------------------------------
__global__ void k_adj_row(const float* __restrict__ emb, const float* __restrict__ adj,
                          const float* __restrict__ alpha_p,
                          float* __restrict__ Araw, float* __restrict__ dvec) {
    int r = blockIdx.x;
    int lane = threadIdx.x;
    __shared__ float er[HH];
    __shared__ float la[NN];
    __shared__ float tmp[NN];
    __shared__ float keep[NN];
    er[lane] = emb[r*HH + lane];
    __syncthreads();
    for (int j = lane; j < NN; j += 64) {
        float d = 0.f;
        #pragma unroll 8
        for (int h = 0; h < HH; ++h) d += er[h] * emb[j*HH + h];
        float v = fmaxf(d, 0.f);
        la[j] = v; tmp[j] = v; keep[j] = 0.f;
    }
    __syncthreads();
    for (int it = 0; it < KK; ++it) {
        float bv = -1.f; int bi = NN;
        for (int j = lane; j < NN; j += 64) {
            float v = tmp[j];
            if (v > bv) { bv = v; bi = j; }
        }
        #pragma unroll
        for (int off = 32; off > 0; off >>= 1) {
            float ov = __shfl_xor(bv, off, 64);
            int   oi = __shfl_xor(bi, off, 64);
            if (ov > bv || (ov == bv && oi < bi)) { bv = ov; bi = oi; }
        }
        if (lane == 0) { keep[bi] = 1.f; tmp[bi] = -1.f; }
        __syncthreads();
    }
    float mloc = 0.f;
    for (int j = lane; j < NN; j += 64) {
        float v = (keep[j] > 0.f) ? la[j] : 0.f;
        tmp[j] = v;
        mloc = fmaxf(mloc, v);
    }
    float m = wave_max(mloc);
    float sloc = 0.f;
    for (int j = lane; j < NN; j += 64) sloc += expf(tmp[j] - m);
    float ssum = wave_sum(sloc);
    float alpha = alpha_p[0];
    float rloc = 0.f;
    for (int j = lane; j < NN; j += 64) {
        float soft = expf(tmp[j] - m) / ssum;
        float comb = alpha * adj[r*NN + j] + (1.f - alpha) * soft;
        float a = (j == r) ? 1.f : comb;
        Araw[r*NN + j] = a;
        rloc += a;
    }
    float rs = wave_sum(rloc);
    if (lane == 0) dvec[r] = 1.f / sqrtf(fmaxf(rs, 1.f));
}

__global__ void k_adj_scale(const float* __restrict__ Araw, const float* __restrict__ dvec,
                            float* __restrict__ Amat) {
    int r = blockIdx.x, j = threadIdx.x;
    if (j < NN) Amat[r*NN + j] = Araw[r*NN + j] * dvec[r] * dvec[j];
}

// ---------------------------------------------------------------------------
// Prep: cast tW -> bf16; build padded bf16 adjacency (208x224, zeros in pad);
// build transposed bf16 gcn weights gWT[i][n][k] = gW[i][k][n].
// ---------------------------------------------------------------------------
__global__ void k_prep(const float* __restrict__ tW, const float* __restrict__ gW,
                       const float* __restrict__ Amat, unsigned short* __restrict__ tWb,
                       unsigned short* __restrict__ Ab, unsigned short* __restrict__ gWT) {
    int i = blockIdx.x*256 + threadIdx.x;
    if (i < NBLK*SS*SS) tWb[i] = f2bf(tW[i]);
    if (i < NPAD*KPAD) {
        int m = i / KPAD, k = i % KPAD;
        Ab[i] = (m < NN && k < NN) ? f2bf(Amat[m*NN + k]) : (unsigned short)0;
    }
    if (i < NBLK*HH*HH) {
        int blk = i >> 12, r = (i >> 6) & 63, c = i & 63;
        gWT[i] = f2bf(gW[(blk << 12) + c*HH + r]);
    }
}

// ---------------------------------------------------------------------------
// Prep2 (head): hWT[n][k] = bf16(head_W[k][n]) for k < SH;
//   C1[j=p2*4+f][p] = sum_h fW[f,h]*hW[SH+p2*64+h][p]   (futr branch folded)
//   c0[p] = hb[p] + sum_{p2,h} fb[h]*hW[SH+p2*64+h][p]
// ---------------------------------------------------------------------------
__global__ void k_prep2(const float* __restrict__ hW, const float* __restrict__ fW,
                        const float* __restrict__ fb, const float* __restrict__ hb,
                        unsigned short* __restrict__ hWT, float* __restrict__ C1,
                        float* __restrict__ c0) {
    int i = blockIdx.x*256 + threadIdx.x;
    if (i < PP*SH) {
        int n = i / SH, k = i % SH;
        hWT[i] = f2bf(hW[(size_t)k*PP + n]);
    }
    if (i < PP*FNN*PP) {            // 192*48
        int j = i / PP, p = i % PP;
        int p2 = j >> 2, f = j & 3;
        float s = 0.f;
        #pragma unroll 8
        for (int h = 0; h < HH; ++h)
            s += fW[f*HH + h] * hW[(size_t)(SH + p2*HH + h)*PP + p];
        C1[i] = s;
    }
    if (i < PP) {
        float s = hb[i];
        for (int c = 0; c < PP*HH; ++c)
            s += fb[c & 63] * hW[(size_t)(SH + c)*PP + i];
        c0[i] = s;
    }
}

// ---------------------------------------------------------------------------
// Stage0: InstanceNorm over S -> proj (8->64) -> +emb. bf16 out. Wave per (b,n).
// ---------------------------------------------------------------------------
__global__ void k_stage0(const float* __restrict__ x, const float* __restrict__ inw,
                         const float* __restrict__ inb, const float* __restrict__ pW,
                         const float* __restrict__ pb, const float* __restrict__ emb,
                         unsigned short* __restrict__ X) {
    int bn = blockIdx.x;
    int lane = threadIdx.x;
    int n = bn % NN;
    __shared__ float xl[SS*FIN];
    const float* xp = x + (size_t)bn*SS*FIN;
    for (int i = lane; i < SS*FIN; i += 64) xl[i] = xp[i];
    __syncthreads();
    float sum8[FIN], sq8[FIN];
    #pragma unroll
    for (int f = 0; f < FIN; ++f) { sum8[f] = 0.f; sq8[f] = 0.f; }
    #pragma unroll
    for (int k = 0; k < 3; ++k) {
        int s = lane*3 + k;
        #pragma unroll
        for (int f = 0; f < FIN; ++f) {
            float v = xl[s*FIN + f];
            sum8[f] += v; sq8[f] += v*v;
        }
    }
    #pragma unroll
    for (int f = 0; f < FIN; ++f) { sum8[f] = wave_sum(sum8[f]); sq8[f] = wave_sum(sq8[f]); }
    float scal[FIN], bias[FIN];
    #pragma unroll
    for (int f = 0; f < FIN; ++f) {
        float mu  = sum8[f] * (1.f/SS);
        float var = sq8[f] * (1.f/SS) - mu*mu;
        float sc  = inw[f] / sqrtf(var + EPSF);
        scal[f] = sc;
        bias[f] = inb[f] - mu*sc;
    }
    float pwr[FIN];
    #pragma unroll
    for (int f = 0; f < FIN; ++f) pwr[f] = pW[f*HH + lane];
    float cst = pb[lane] + emb[n*HH + lane];
    unsigned short* op = X + (size_t)bn*SH;
    for (int s = 0; s < SS; ++s) {
        float acc = cst;
        #pragma unroll
        for (int f = 0; f < FIN; ++f) acc += (xl[s*FIN + f]*scal[f] + bias[f]) * pwr[f];
        op[s*HH + lane] = f2bf(acc);
    }
}

// ---------------------------------------------------------------------------
// Temporal MFMA (IN-PLACE): x[t,h] += gelu( W@x + tb )
// Block per (b,n). xT (transposed x) in LDS; W-frags direct from global (L2-hot).
// GELU via tanh-form (max dev ~3e-4 vs exact erf).
// ---------------------------------------------------------------------------
#define TPITCH 200
__global__ __launch_bounds__(256) void k_temporal_mfma(unsigned short* __restrict__ X,
        const unsigned short* __restrict__ Wb, const float* __restrict__ tb) {
    __shared__ unsigned short xT[HH * TPITCH];   // 25.6 KB
    int bn = blockIdx.x, tid = threadIdx.x;
    unsigned short* xp = X + (size_t)bn*SH;
    const unsigned int* xp32 = (const unsigned int*)xp;
    for (int i = tid; i < SH/2; i += 256) {
        unsigned int u = xp32[i];
        int s = i >> 5, hp = i & 31;
        xT[(2*hp)*TPITCH + s]   = (unsigned short)(u & 0xffffu);
        xT[(2*hp+1)*TPITCH + s] = (unsigned short)(u >> 16);
    }
    __syncthreads();
    int lane = tid & 63, w = tid >> 6;
    int col = lane & 15, q = lane >> 4;
    f32x4 acc[3][4];
    #pragma unroll
    for (int tt = 0; tt < 3; ++tt)
        #pragma unroll
        for (int ht = 0; ht < 4; ++ht) acc[tt][ht] = (f32x4){0.f,0.f,0.f,0.f};

    #pragma unroll 2
    for (int k0 = 0; k0 < SS; k0 += 32) {
        bf16x8 a[3], b[4];
        #pragma unroll
        for (int tt = 0; tt < 3; ++tt)
            a[tt] = *(const bf16x8*)(Wb + (size_t)(w*48 + tt*16 + col)*SS + k0 + q*8);
        #pragma unroll
        for (int ht = 0; ht < 4; ++ht)
            b[ht] = *(const bf16x8*)(&xT[(ht*16 + col)*TPITCH + k0 + q*8]);
        #pragma unroll
        for (int tt = 0; tt < 3; ++tt)
            #pragma unroll
            for (int ht = 0; ht < 4; ++ht)
                acc[tt][ht] = __builtin_amdgcn_mfma_f32_16x16x32_bf16(a[tt], b[ht], acc[tt][ht], 0, 0, 0);
    }
    #pragma unroll
    for (int tt = 0; tt < 3; ++tt) {
        int t0 = w*48 + tt*16 + q*4;
        float tbv[4];
        #pragma unroll
        for (int r = 0; r < 4; ++r) tbv[r] = tb[t0 + r];
        #pragma unroll
        for (int ht = 0; ht < 4; ++ht) {
            int h = ht*16 + col;
            const unsigned short* rp = &xT[h*TPITCH + t0];
            #pragma unroll
            for (int r = 0; r < 4; ++r) {
                float y = acc[tt][ht][r] + tbv[r];
                // gelu(y) ~= y * sigmoid(2*0.7978845608*(y + 0.044715 y^3))
                float u2 = y * (1.5957691216f + 0.07135481626f*y*y);
                float g = y / (1.f + __expf(-u2));
                xp[(t0 + r)*HH + h] = f2bf(bf2f(rp[r]) + g);
            }
        }
    }
}

// ---------------------------------------------------------------------------
// Fused spatial (IN-PLACE on X), block = (sp-pair, b), 512 threads (8 waves):
//   waves 0-3 own timestep sp0, waves 4-7 own sp0+1.
//   z[node,h] = sum_n A[node,n] x[b,n,sp,h]        (MFMA1, K=224)
//   y[node,h'] = z[node,:] @ gcn_W                 (MFMA2, K=64)
//   x = LN_h'( x + y + gb ) * ln_w + ln_b
// Two timesteps per block make every per-node global read/write a 256 B
// contiguous chunk (DRAM granularity fix). LDS union: xT then z.
// ---------------------------------------------------------------------------
__global__ __launch_bounds__(512) void k_spatial_fused(unsigned short* __restrict__ X,
        const unsigned short* __restrict__ Ab, const unsigned short* __restrict__ gWT,
        const float* __restrict__ gb, const float* __restrict__ lnw,
        const float* __restrict__ lnb) {
    __shared__ unsigned short smem[SM2];         // 59.9 KB (xT then zl)
    int spq = blockIdx.x, b = blockIdx.y, tid = threadIdx.x;
    unsigned short* xbase = X + (size_t)b*NN*SH + spq*128;   // 2 timesteps
    const unsigned int* xp32 = (const unsigned int*)xbase;
    // stage transpose: xT[sp*64 + h][n] = X[b][n][spq*128 + sp*64 + h]
    // per node: one 256 B contiguous read (64 dwords)
    for (int i = tid; i < NN*64; i += 512) {
        int n = i >> 6, d = i & 63;
        unsigned int u = xp32[(size_t)n*(SH/2) + d];
        int sp = d >> 5, hp = d & 31;
        smem[(sp*64 + 2*hp)*XP2 + n]   = (unsigned short)(u & 0xffffu);
        smem[(sp*64 + 2*hp+1)*XP2 + n] = (unsigned short)(u >> 16);
    }
    for (int i = tid; i < 128*(KPAD-NN); i += 512)
        smem[(i/(KPAD-NN))*XP2 + NN + (i%(KPAD-NN))] = 0;   // zero K-pad
    __syncthreads();
    int lane = tid & 63, w = tid >> 6;           // w in 0..7
    int col = lane & 15, q = lane >> 4;
    int sp = w >> 2, wl = w & 3;                 // timestep-local wave 0..3
    // MFMA1: D1[m=h (tile wl)][n=node] = sum_n' xT[h][n'] * Ab[node][n']
    f32x4 acc1[13];
    #pragma unroll
    for (int nt = 0; nt < 13; ++nt) acc1[nt] = (f32x4){0.f,0.f,0.f,0.f};
    for (int k0 = 0; k0 < KPAD; k0 += 32) {
        bf16x8 a = *(const bf16x8*)(&smem[(sp*64 + wl*16 + col)*XP2 + k0 + q*8]);
        #pragma unroll
        for (int nt = 0; nt < 13; ++nt) {
            bf16x8 bb = *(const bf16x8*)(Ab + (size_t)(nt*16 + col)*KPAD + k0 + q*8);
            acc1[nt] = __builtin_amdgcn_mfma_f32_16x16x32_bf16(a, bb, acc1[nt], 0, 0, 0);
        }
    }
    // hoist residual into VGPRs before xT is overwritten:
    // res[j][nt2] packs x[node = mt*16+q*4 .. +3][h' = nt2*16+col], mt = wl+4j
    unsigned long long res[4][4];
    #pragma unroll
    for (int j = 0; j < 4; ++j) {
        int mt = wl + 4*j;
        if (mt < 13) {
            #pragma unroll
            for (int nt2 = 0; nt2 < 4; ++nt2)
                res[j][nt2] = *(const unsigned long long*)
                    (&smem[(sp*64 + nt2*16 + col)*XP2 + mt*16 + q*4]);
        }
    }
    __syncthreads();
    // z overwrite: zl[sp*208 + node][h], node = nt*16+col, h = wl*16+q*4+{0..3}
    #pragma unroll
    for (int nt = 0; nt < 13; ++nt) {
        unsigned long long pk =
              (unsigned long long)f2bf(acc1[nt][0])
            | ((unsigned long long)f2bf(acc1[nt][1]) << 16)
            | ((unsigned long long)f2bf(acc1[nt][2]) << 32)
            | ((unsigned long long)f2bf(acc1[nt][3]) << 48);
        *(unsigned long long*)(&smem[(sp*208 + nt*16 + col)*ZPITCH + wl*16 + q*4]) = pk;
    }
    __syncthreads();
    // per-lane LN params at h' = nt2*16+col
    float gbv[4], lwv[4], lbv[4];
    #pragma unroll
    for (int nt2 = 0; nt2 < 4; ++nt2) {
        int h = nt2*16 + col;
        gbv[nt2] = gb[h]; lwv[nt2] = lnw[h]; lbv[nt2] = lnb[h];
    }
    unsigned short* xsp = xbase + sp*64;
    // MFMA2 + LN + store; mt = node-tile
    #pragma unroll
    for (int j = 0; j < 4; ++j) {
        int mt = wl + 4*j;
        if (mt >= 13) break;
        f32x4 acc2[4];
        #pragma unroll
        for (int nt2 = 0; nt2 < 4; ++nt2) acc2[nt2] = (f32x4){0.f,0.f,0.f,0.f};
        #pragma unroll
        for (int k0 = 0; k0 < HH; k0 += 32) {
            bf16x8 a = *(const bf16x8*)(&smem[(sp*208 + mt*16 + col)*ZPITCH + k0 + q*8]);
            #pragma unroll
            for (int nt2 = 0; nt2 < 4; ++nt2) {
                bf16x8 bw = *(const bf16x8*)(gWT + (size_t)(nt2*16 + col)*HH + k0 + q*8);
                acc2[nt2] = __builtin_amdgcn_mfma_f32_16x16x32_bf16(a, bw, acc2[nt2], 0, 0, 0);
            }
        }
        float v[4][4];
        float sv[4] = {0.f,0.f,0.f,0.f}, sq[4] = {0.f,0.f,0.f,0.f};
        #pragma unroll
        for (int nt2 = 0; nt2 < 4; ++nt2) {
            unsigned long long rr = res[j][nt2];
            #pragma unroll
            for (int r = 0; r < 4; ++r) {
                float t = acc2[nt2][r] + bf2f((unsigned short)(rr >> (16*r))) + gbv[nt2];
                v[nt2][r] = t; sv[r] += t; sq[r] += t*t;
            }
        }
        #pragma unroll
        for (int r = 0; r < 4; ++r) {
            #pragma unroll
            for (int off = 1; off < 16; off <<= 1) {
                sv[r] += __shfl_xor(sv[r], off, 64);
                sq[r] += __shfl_xor(sq[r], off, 64);
            }
        }
        #pragma unroll
        for (int r = 0; r < 4; ++r) {
            int node = mt*16 + q*4 + r;
            if (node < NN) {
                float mu  = sv[r] * (1.f/64.f);
                float var = sq[r] * (1.f/64.f) - mu*mu;
                float rstd = 1.f / sqrtf(var + EPSF);
                #pragma unroll
                for (int nt2 = 0; nt2 < 4; ++nt2) {
                    float o = (v[nt2][r] - mu) * rstd * lwv[nt2] + lbv[nt2];
                    xsp[(size_t)node*SH + nt2*16 + col] = f2bf(o);
                }
            }
        }
    }
}

// ---------------------------------------------------------------------------
// Head futr+bias: out[row,p] = c0[p] + xfut[row,:192] @ C1   (plain writes,
// runs BEFORE k_head_mfma which atomically accumulates the hist GEMM)
// ---------------------------------------------------------------------------
__global__ __launch_bounds__(192) void k_head_futr(const float* __restrict__ xfut,
        const float* __restrict__ C1, const float* __restrict__ c0,
        float* __restrict__ out) {
    __shared__ float C1l[192*PP];   // 36.8 KB
    __shared__ float xfl[4*192];    // 3 KB
    int tid = threadIdx.x;
    int r0 = blockIdx.x * 4;
    for (int i = tid; i < 192*PP; i += 192) C1l[i] = C1[i];
    for (int i = tid; i < 4*192; i += 192) xfl[i] = xfut[(size_t)r0*192 + i];
    __syncthreads();
    int p = tid % PP, rr = tid / PP;
    float acc = c0[p];
    #pragma unroll 8
    for (int j = 0; j < 192; ++j) acc += xfl[rr*192 + j] * C1l[j*PP + p];
    out[(size_t)(r0 + rr)*PP + p] = acc;
}

// ---------------------------------------------------------------------------
// Head hist GEMM (bf16 MFMA): out[row,p] += X[row,:12288] @ hWT^T
// A-op = X rows straight from global; B-op = hWT (L2-hot). Split-K x8.
// ---------------------------------------------------------------------------
#define KSL 1536
__global__ __launch_bounds__(256) void k_head_mfma(const unsigned short* __restrict__ X,
        const unsigned short* __restrict__ hWT, float* __restrict__ out) {
    int tid = threadIdx.x;
    int lane = tid & 63, w = tid >> 6;
    int col = lane & 15, q = lane >> 4;
    int m0 = blockIdx.x*64 + w*16;
    int k0 = blockIdx.y*KSL;
    const unsigned short* xp = X + (size_t)(m0 + col)*SH + k0 + q*8;
    const unsigned short* wp = hWT + (size_t)col*SH + k0 + q*8;
    f32x4 acc[3];
    #pragma unroll
    for (int nt = 0; nt < 3; ++nt) acc[nt] = (f32x4){0.f,0.f,0.f,0.f};
    #pragma unroll 4
    for (int kk = 0; kk < KSL; kk += 32) {
        bf16x8 a = *(const bf16x8*)(xp + kk);
        #pragma unroll
        for (int nt = 0; nt < 3; ++nt) {
            bf16x8 b = *(const bf16x8*)(wp + (size_t)nt*16*SH + kk);
            acc[nt] = __builtin_amdgcn_mfma_f32_16x16x32_bf16(a, b, acc[nt], 0, 0, 0);
        }
    }
    int orow = m0 + q*4;
    #pragma unroll
    for (int nt = 0; nt < 3; ++nt)
        #pragma unroll
        for (int r = 0; r < 4; ++r)
            atomicAdd(&out[(size_t)(orow + r)*PP + nt*16 + col], acc[nt][r]);
}

// ---------------------------------------------------------------------------
extern "C" void kernel_launch(void* const* d_in, const int* in_sizes, int n_in,
                              void* d_out, int out_size, void* d_ws, size_t ws_size,
                              hipStream_t stream) {
    const float* x     = (const float*)d_in[0];
    const float* xfut  = (const float*)d_in[1];
    const float* adj   = (const float*)d_in[2];
    const float* emb   = (const float*)d_in[3];
    const float* alpha = (const float*)d_in[4];
    const float* inw   = (const float*)d_in[5];
    const float* inb   = (const float*)d_in[6];
    const float* pW    = (const float*)d_in[7];
    const float* pb    = (const float*)d_in[8];
    const float* tW    = (const float*)d_in[9];
    const float* tb    = (const float*)d_in[10];
    const float* gW    = (const float*)d_in[11];
    const float* gb    = (const float*)d_in[12];
    const float* lnw   = (const float*)d_in[13];
    const float* lnb   = (const float*)d_in[14];
    const float* fW    = (const float*)d_in[15];
    const float* fb    = (const float*)d_in[16];
    const float* hW    = (const float*)d_in[17];
    const float* hb    = (const float*)d_in[18];
    float* out = (float*)d_out;

    // Workspace layout (~160 MB): bufX 157.3MB + adjacency/weights ~1.6MB
    unsigned short* bufX = (unsigned short*)d_ws;
    float* Amat = (float*)(bufX + XSZ);
    float* Araw = Amat + NN*NN;
    float* dvec = Araw + NN*NN;
    unsigned short* tWb = (unsigned short*)(dvec + NN);
    unsigned short* Ab  = tWb + NBLK*SS*SS;
    unsigned short* gWT = Ab + NPAD*KPAD;
    unsigned short* hWT = gWT + NBLK*HH*HH;
    float* C1 = (float*)(hWT + (size_t)PP*SH);
    float* c0 = C1 + 192*PP;

    k_adj_row<<<NN, 64, 0, stream>>>(emb, adj, alpha, Araw, dvec);
    k_adj_scale<<<NN, 256, 0, stream>>>(Araw, dvec, Amat);
    k_prep<<<(NBLK*SS*SS + 255)/256, 256, 0, stream>>>(tW, gW, Amat, tWb, Ab, gWT);
    k_prep2<<<((size_t)PP*SH + 255)/256, 256, 0, stream>>>(hW, fW, fb, hb, hWT, C1, c0);
    k_stage0<<<ROWS, 64, 0, stream>>>(x, inw, inb, pW, pb, emb, bufX);

    for (int i = 0; i < NBLK; ++i) {
        k_temporal_mfma<<<ROWS, 256, 0, stream>>>(bufX, tWb + (size_t)i*SS*SS, tb + i*SS);
        k_spatial_fused<<<dim3(SS/2, BB), 512, 0, stream>>>(bufX, Ab, gWT + (size_t)i*HH*HH,
                                                            gb + i*HH, lnw + i*HH, lnb + i*HH);
    }
    k_head_futr<<<ROWS/4, 192, 0, stream>>>(xfut, C1, c0, out);
    k_head_mfma<<<dim3(ROWS/64, 8), 256, 0, stream>>>(bufX, hWT, out);
}

// Round 9
// 1196.169 us; speedup vs baseline: 1.2376x; 1.2376x over previous
//
#include <hip/hip_runtime.h>
#include <math.h>

// Problem constants
#define BB   32
#define NN   200
#define SS   192
#define FIN  8
#define HH   64
#define PP   48
#define FNN  4
#define KK   10
#define NBLK 3
#define EPSF 1e-5f
#define SH   (SS*HH)               // 12288
#define XSZ  ((size_t)BB*NN*SS*HH) // 78,643,200 elements
#define ROWS (BB*NN)               // 6400
#define NPAD 208                   // node dim padded
#define KPAD 224                   // node contraction padded (7 x 32)

// --- fused-spatial LDS geometry ---
// xT: 64 rows x 256 u16, XOR-swizzled 8-elem chunks (chunk ^= row&31)
// z : 208 rows x 72 u16 (union with xT region, overwritten after MFMA1)
// As: 208 rows x 40 u16 (one 32-wide adjacency K-slice); reused for gw (64x72)
#define XTW   256
#define ZP    72
#define ASP   40
#define GWP   72
#define ASOFF 16384                // u16 offset of As/gw region
#define ASOFF32 8192               // dword offset
#define SMTOT (16384 + 8320)       // 24704 u16 = 49408 B

typedef __attribute__((ext_vector_type(8))) short bf16x8;
typedef __attribute__((ext_vector_type(4))) float f32x4;

// bf16 <-> f32 helpers on raw ushort storage
__device__ __forceinline__ float bf2f(unsigned short u) {
    union { unsigned int i; float f; } v; v.i = ((unsigned int)u) << 16; return v.f;
}
__device__ __forceinline__ unsigned short f2bf(float f) {
    union { float f; unsigned int i; } v; v.f = f;
    unsigned int r = v.i + 0x7FFFu + ((v.i >> 16) & 1u);   // round-nearest-even
    return (unsigned short)(r >> 16);
}

__device__ __forceinline__ float wave_sum(float v) {
    #pragma unroll
    for (int off = 32; off > 0; off >>= 1) v += __shfl_xor(v, off, 64);
    return v;
}
__device__ __forceinline__ float wave_max(float v) {
    #pragma unroll
    for (int off = 32; off > 0; off >>= 1) v = fmaxf(v, __shfl_xor(v, off, 64));
    return v;
}

// ---------------------------------------------------------------------------
// Adjacency: la = relu(E E^T); top-K mask; softmax; blend with adj; diag=1;
// store un-normalized row + d_r. One wave per row.
// ---------------------------------------------------------------------------
__global__ void k_adj_row(const float* __restrict__ emb, const float* __restrict__ adj,
                          const float* __restrict__ alpha_p,
                          float* __restrict__ Araw, float* __restrict__ dvec) {
    int r = blockIdx.x;
    int lane = threadIdx.x;
    __shared__ float er[HH];
    __shared__ float la[NN];
    __shared__ float tmp[NN];
    __shared__ float keep[NN];
    er[lane] = emb[r*HH + lane];
    __syncthreads();
    for (int j = lane; j < NN; j += 64) {
        float d = 0.f;
        #pragma unroll 8
        for (int h = 0; h < HH; ++h) d += er[h] * emb[j*HH + h];
        float v = fmaxf(d, 0.f);
        la[j] = v; tmp[j] = v; keep[j] = 0.f;
    }
    __syncthreads();
    for (int it = 0; it < KK; ++it) {
        float bv = -1.f; int bi = NN;
        for (int j = lane; j < NN; j += 64) {
            float v = tmp[j];
            if (v > bv) { bv = v; bi = j; }
        }
        #pragma unroll
        for (int off = 32; off > 0; off >>= 1) {
            float ov = __shfl_xor(bv, off, 64);
            int   oi = __shfl_xor(bi, off, 64);
            if (ov > bv || (ov == bv && oi < bi)) { bv = ov; bi = oi; }
        }
        if (lane == 0) { keep[bi] = 1.f; tmp[bi] = -1.f; }
        __syncthreads();
    }
    float mloc = 0.f;
    for (int j = lane; j < NN; j += 64) {
        float v = (keep[j] > 0.f) ? la[j] : 0.f;
        tmp[j] = v;
        mloc = fmaxf(mloc, v);
    }
    float m = wave_max(mloc);
    float sloc = 0.f;
    for (int j = lane; j < NN; j += 64) sloc += expf(tmp[j] - m);
    float ssum = wave_sum(sloc);
    float alpha = alpha_p[0];
    float rloc = 0.f;
    for (int j = lane; j < NN; j += 64) {
        float soft = expf(tmp[j] - m) / ssum;
        float comb = alpha * adj[r*NN + j] + (1.f - alpha) * soft;
        float a = (j == r) ? 1.f : comb;
        Araw[r*NN + j] = a;
        rloc += a;
    }
    float rs = wave_sum(rloc);
    if (lane == 0) dvec[r] = 1.f / sqrtf(fmaxf(rs, 1.f));
}

__global__ void k_adj_scale(const float* __restrict__ Araw, const float* __restrict__ dvec,
                            float* __restrict__ Amat) {
    int r = blockIdx.x, j = threadIdx.x;
    if (j < NN) Amat[r*NN + j] = Araw[r*NN + j] * dvec[r] * dvec[j];
}

// ---------------------------------------------------------------------------
// Prep: cast tW -> bf16; build padded bf16 adjacency (208x224, zeros in pad);
// build transposed bf16 gcn weights gWT[i][n][k] = gW[i][k][n].
// ---------------------------------------------------------------------------
__global__ void k_prep(const float* __restrict__ tW, const float* __restrict__ gW,
                       const float* __restrict__ Amat, unsigned short* __restrict__ tWb,
                       unsigned short* __restrict__ Ab, unsigned short* __restrict__ gWT) {
    int i = blockIdx.x*256 + threadIdx.x;
    if (i < NBLK*SS*SS) tWb[i] = f2bf(tW[i]);
    if (i < NPAD*KPAD) {
        int m = i / KPAD, k = i % KPAD;
        Ab[i] = (m < NN && k < NN) ? f2bf(Amat[m*NN + k]) : (unsigned short)0;
    }
    if (i < NBLK*HH*HH) {
        int blk = i >> 12, r = (i >> 6) & 63, c = i & 63;
        gWT[i] = f2bf(gW[(blk << 12) + c*HH + r]);
    }
}

// ---------------------------------------------------------------------------
// Prep2 (head): hWT[n][k] = bf16(head_W[k][n]) for k < SH;
//   C1[j=p2*4+f][p] = sum_h fW[f,h]*hW[SH+p2*64+h][p]   (futr branch folded)
//   c0[p] = hb[p] + sum_{p2,h} fb[h]*hW[SH+p2*64+h][p]
// ---------------------------------------------------------------------------
__global__ void k_prep2(const float* __restrict__ hW, const float* __restrict__ fW,
                        const float* __restrict__ fb, const float* __restrict__ hb,
                        unsigned short* __restrict__ hWT, float* __restrict__ C1,
                        float* __restrict__ c0) {
    int i = blockIdx.x*256 + threadIdx.x;
    if (i < PP*SH) {
        int n = i / SH, k = i % SH;
        hWT[i] = f2bf(hW[(size_t)k*PP + n]);
    }
    if (i < PP*FNN*PP) {            // 192*48
        int j = i / PP, p = i % PP;
        int p2 = j >> 2, f = j & 3;
        float s = 0.f;
        #pragma unroll 8
        for (int h = 0; h < HH; ++h)
            s += fW[f*HH + h] * hW[(size_t)(SH + p2*HH + h)*PP + p];
        C1[i] = s;
    }
    if (i < PP) {
        float s = hb[i];
        for (int c = 0; c < PP*HH; ++c)
            s += fb[c & 63] * hW[(size_t)(SH + c)*PP + i];
        c0[i] = s;
    }
}

// ---------------------------------------------------------------------------
// Stage0: InstanceNorm over S -> proj (8->64) -> +emb. bf16 out. Wave per (b,n).
// ---------------------------------------------------------------------------
__global__ void k_stage0(const float* __restrict__ x, const float* __restrict__ inw,
                         const float* __restrict__ inb, const float* __restrict__ pW,
                         const float* __restrict__ pb, const float* __restrict__ emb,
                         unsigned short* __restrict__ X) {
    int bn = blockIdx.x;
    int lane = threadIdx.x;
    int n = bn % NN;
    __shared__ float xl[SS*FIN];
    const float* xp = x + (size_t)bn*SS*FIN;
    for (int i = lane; i < SS*FIN; i += 64) xl[i] = xp[i];
    __syncthreads();
    float sum8[FIN], sq8[FIN];
    #pragma unroll
    for (int f = 0; f < FIN; ++f) { sum8[f] = 0.f; sq8[f] = 0.f; }
    #pragma unroll
    for (int k = 0; k < 3; ++k) {
        int s = lane*3 + k;
        #pragma unroll
        for (int f = 0; f < FIN; ++f) {
            float v = xl[s*FIN + f];
            sum8[f] += v; sq8[f] += v*v;
        }
    }
    #pragma unroll
    for (int f = 0; f < FIN; ++f) { sum8[f] = wave_sum(sum8[f]); sq8[f] = wave_sum(sq8[f]); }
    float scal[FIN], bias[FIN];
    #pragma unroll
    for (int f = 0; f < FIN; ++f) {
        float mu  = sum8[f] * (1.f/SS);
        float var = sq8[f] * (1.f/SS) - mu*mu;
        float sc  = inw[f] / sqrtf(var + EPSF);
        scal[f] = sc;
        bias[f] = inb[f] - mu*sc;
    }
    float pwr[FIN];
    #pragma unroll
    for (int f = 0; f < FIN; ++f) pwr[f] = pW[f*HH + lane];
    float cst = pb[lane] + emb[n*HH + lane];
    unsigned short* op = X + (size_t)bn*SH;
    for (int s = 0; s < SS; ++s) {
        float acc = cst;
        #pragma unroll
        for (int f = 0; f < FIN; ++f) acc += (xl[s*FIN + f]*scal[f] + bias[f]) * pwr[f];
        op[s*HH + lane] = f2bf(acc);
    }
}

// ---------------------------------------------------------------------------
// Temporal MFMA (IN-PLACE): x[t,h] += gelu( W@x + tb )
// Block per (b,n). xT (transposed x) in LDS; W-frags direct from global (L2-hot).
// GELU via tanh-form (max dev ~3e-4 vs exact erf).
// ---------------------------------------------------------------------------
#define TPITCH 200
__global__ __launch_bounds__(256) void k_temporal_mfma(unsigned short* __restrict__ X,
        const unsigned short* __restrict__ Wb, const float* __restrict__ tb) {
    __shared__ unsigned short xT[HH * TPITCH];   // 25.6 KB
    int bn = blockIdx.x, tid = threadIdx.x;
    unsigned short* xp = X + (size_t)bn*SH;
    const unsigned int* xp32 = (const unsigned int*)xp;
    for (int i = tid; i < SH/2; i += 256) {
        unsigned int u = xp32[i];
        int s = i >> 5, hp = i & 31;
        xT[(2*hp)*TPITCH + s]   = (unsigned short)(u & 0xffffu);
        xT[(2*hp+1)*TPITCH + s] = (unsigned short)(u >> 16);
    }
    __syncthreads();
    int lane = tid & 63, w = tid >> 6;
    int col = lane & 15, q = lane >> 4;
    f32x4 acc[3][4];
    #pragma unroll
    for (int tt = 0; tt < 3; ++tt)
        #pragma unroll
        for (int ht = 0; ht < 4; ++ht) acc[tt][ht] = (f32x4){0.f,0.f,0.f,0.f};

    #pragma unroll 2
    for (int k0 = 0; k0 < SS; k0 += 32) {
        bf16x8 a[3], b[4];
        #pragma unroll
        for (int tt = 0; tt < 3; ++tt)
            a[tt] = *(const bf16x8*)(Wb + (size_t)(w*48 + tt*16 + col)*SS + k0 + q*8);
        #pragma unroll
        for (int ht = 0; ht < 4; ++ht)
            b[ht] = *(const bf16x8*)(&xT[(ht*16 + col)*TPITCH + k0 + q*8]);
        #pragma unroll
        for (int tt = 0; tt < 3; ++tt)
            #pragma unroll
            for (int ht = 0; ht < 4; ++ht)
                acc[tt][ht] = __builtin_amdgcn_mfma_f32_16x16x32_bf16(a[tt], b[ht], acc[tt][ht], 0, 0, 0);
    }
    #pragma unroll
    for (int tt = 0; tt < 3; ++tt) {
        int t0 = w*48 + tt*16 + q*4;
        float tbv[4];
        #pragma unroll
        for (int r = 0; r < 4; ++r) tbv[r] = tb[t0 + r];
        #pragma unroll
        for (int ht = 0; ht < 4; ++ht) {
            int h = ht*16 + col;
            const unsigned short* rp = &xT[h*TPITCH + t0];
            #pragma unroll
            for (int r = 0; r < 4; ++r) {
                float y = acc[tt][ht][r] + tbv[r];
                // gelu(y) ~= y * sigmoid(2*0.7978845608*(y + 0.044715 y^3))
                float u2 = y * (1.5957691216f + 0.07135481626f*y*y);
                float g = y / (1.f + __expf(-u2));
                xp[(t0 + r)*HH + h] = f2bf(bf2f(rp[r]) + g);
            }
        }
    }
}

// ---------------------------------------------------------------------------
// Fused spatial (IN-PLACE on X), block = (s', b), 256 threads / 4 waves:
//   z[node,h] = sum_n A[node,n] x[b,n,s',h]        (MFMA1, K=224)
//   y[node,h'] = z[node,:] @ gcn_W                 (MFMA2, K=64)
//   x = LN_h'( x + y + gb ) * ln_w + ln_b
// R8 changes: (a) adjacency K-slices LDS-staged w/ register prefetch
// (cuts 2.3 GB/dispatch of per-wave L2 reads 4x, removes load->MFMA dep);
// (b) XOR-swizzled xT (conflict-free staging); (c) LN output bounced through
// LDS, written out as full 128 B lines per node.
// ---------------------------------------------------------------------------
__global__ __launch_bounds__(256, 3) void k_spatial_fused(unsigned short* __restrict__ X,
        const unsigned short* __restrict__ Ab, const unsigned short* __restrict__ gWT,
        const float* __restrict__ gb, const float* __restrict__ lnw,
        const float* __restrict__ lnb) {
    __shared__ unsigned short smem[SMTOT];       // 49.4 KB
    unsigned int* sm32 = (unsigned int*)smem;
    int sp = blockIdx.x, b = blockIdx.y, tid = threadIdx.x;
    unsigned short* xbase = X + (size_t)b*NN*SH + sp*HH;
    const unsigned int* xp32 = (const unsigned int*)xbase;
    const unsigned int* Ab32 = (const unsigned int*)Ab;
    const unsigned int* gW32 = (const unsigned int*)gWT;

    // ---- stage xT swizzled: elem (h,n) at u16 [h*256 + ((n>>3 ^ (h&31))<<3) + (n&7)]
    // dword-pair micro-transpose: conflict-free dword LDS writes, 128 B global reads
    for (int i = tid; i < 100*32; i += 256) {
        int np = i >> 5, dd = i & 31;            // node pair, dword col
        unsigned int u0 = xp32[(size_t)(2*np)*(SH/2) + dd];
        unsigned int u1 = xp32[(size_t)(2*np+1)*(SH/2) + dd];
        int r0 = 2*dd, r1 = 2*dd + 1;
        unsigned int lo = (u0 & 0xffffu) | (u1 << 16);
        unsigned int hi = (u0 >> 16) | (u1 & 0xffff0000u);
        sm32[r0*128 + ((((np>>2)) ^ (r0&31))<<2) + (np&3)] = lo;
        sm32[r1*128 + ((((np>>2)) ^ (r1&31))<<2) + (np&3)] = hi;
    }
    // zero-pad node cols 200..223 (dword cols 100..111)
    for (int i = tid; i < 64*12; i += 256) {
        int r = i / 12, kdw = 100 + (i % 12);
        sm32[r*128 + (((kdw>>2) ^ (r&31))<<2) + (kdw&3)] = 0;
    }
    // stage adjacency K-slice 0 (Ab[node][0..31])
    for (int i = tid; i < NPAD*16; i += 256) {
        int node = i >> 4, dw = i & 15;
        sm32[ASOFF32 + node*20 + dw] = Ab32[node*112 + dw];
    }
    __syncthreads();

    int lane = tid & 63, w = tid >> 6;
    int col = lane & 15, q = lane >> 4;
    int arow = w*16 + col;                       // xT row for MFMA1 A-frag

    // ---- MFMA1 with As prefetch pipeline ----
    f32x4 acc1[13];
    #pragma unroll
    for (int nt = 0; nt < 13; ++nt) acc1[nt] = (f32x4){0.f,0.f,0.f,0.f};
    unsigned int pf[13];
    for (int step = 0; step < 7; ++step) {
        if (step < 6) {
            int kb = (step + 1) * 16;            // dword offset into Ab row
            #pragma unroll
            for (int it = 0; it < 13; ++it) {
                int idx = tid + it*256;
                pf[it] = Ab32[(idx>>4)*112 + kb + (idx&15)];
            }
        }
        int cb = step*4;                          // chunk base = k0>>3
        bf16x8 a = *(const bf16x8*)(&smem[arow*XTW + (((cb + q) ^ (arow&31))<<3)]);
        #pragma unroll
        for (int nt = 0; nt < 13; ++nt) {
            bf16x8 bb = *(const bf16x8*)(&smem[ASOFF + (nt*16 + col)*ASP + q*8]);
            acc1[nt] = __builtin_amdgcn_mfma_f32_16x16x32_bf16(a, bb, acc1[nt], 0, 0, 0);
        }
        __syncthreads();                          // As consumed by all waves
        if (step < 6) {
            #pragma unroll
            for (int it = 0; it < 13; ++it) {
                int idx = tid + it*256;
                sm32[ASOFF32 + (idx>>4)*20 + (idx&15)] = pf[it];
            }
        }
        __syncthreads();                          // As slice ready
    }

    // ---- hoist residual x[node][h'] from xT before overwrite ----
    unsigned long long res[4][4];
    #pragma unroll
    for (int j = 0; j < 4; ++j) {
        int mt = w + 4*j;
        if (mt < 13) {
            #pragma unroll
            for (int nt2 = 0; nt2 < 4; ++nt2) {
                int rr = nt2*16 + col;            // xT row (h')
                int k  = mt*16 + q*4;             // node col
                res[j][nt2] = *(const unsigned long long*)
                    (&smem[rr*XTW + (((k>>3) ^ (rr&31))<<3) + (k&7)]);
            }
        }
    }
    __syncthreads();
    // ---- write z (union over xT region) + stage gcn_W into As region ----
    #pragma unroll
    for (int nt = 0; nt < 13; ++nt) {
        unsigned long long pk =
              (unsigned long long)f2bf(acc1[nt][0])
            | ((unsigned long long)f2bf(acc1[nt][1]) << 16)
            | ((unsigned long long)f2bf(acc1[nt][2]) << 32)
            | ((unsigned long long)f2bf(acc1[nt][3]) << 48);
        *(unsigned long long*)(&smem[(nt*16 + col)*ZP + w*16 + q*4]) = pk;
    }
    for (int i = tid; i < 64*32; i += 256) {
        int n2 = i >> 5, kdw = i & 31;
        sm32[ASOFF32 + n2*36 + kdw] = gW32[n2*32 + kdw];
    }
    __syncthreads();

    // ---- MFMA2 + LN; results written back into z region (own rows) ----
    float gbv[4], lwv[4], lbv[4];
    #pragma unroll
    for (int nt2 = 0; nt2 < 4; ++nt2) {
        int h = nt2*16 + col;
        gbv[nt2] = gb[h]; lwv[nt2] = lnw[h]; lbv[nt2] = lnb[h];
    }
    #pragma unroll
    for (int j = 0; j < 4; ++j) {
        int mt = w + 4*j;
        if (mt >= 13) break;
        f32x4 acc2[4];
        #pragma unroll
        for (int nt2 = 0; nt2 < 4; ++nt2) acc2[nt2] = (f32x4){0.f,0.f,0.f,0.f};
        #pragma unroll
        for (int k0 = 0; k0 < HH; k0 += 32) {
            bf16x8 a = *(const bf16x8*)(&smem[(mt*16 + col)*ZP + k0 + q*8]);
            #pragma unroll
            for (int nt2 = 0; nt2 < 4; ++nt2) {
                bf16x8 bw = *(const bf16x8*)(&smem[ASOFF + (nt2*16 + col)*GWP + k0 + q*8]);
                acc2[nt2] = __builtin_amdgcn_mfma_f32_16x16x32_bf16(a, bw, acc2[nt2], 0, 0, 0);
            }
        }
        float v[4][4];
        float sv[4] = {0.f,0.f,0.f,0.f}, sq[4] = {0.f,0.f,0.f,0.f};
        #pragma unroll
        for (int nt2 = 0; nt2 < 4; ++nt2) {
            unsigned long long rr = res[j][nt2];
            #pragma unroll
            for (int r = 0; r < 4; ++r) {
                float t = acc2[nt2][r] + bf2f((unsigned short)(rr >> (16*r))) + gbv[nt2];
                v[nt2][r] = t; sv[r] += t; sq[r] += t*t;
            }
        }
        #pragma unroll
        for (int r = 0; r < 4; ++r) {
            #pragma unroll
            for (int off = 1; off < 16; off <<= 1) {
                sv[r] += __shfl_xor(sv[r], off, 64);
                sq[r] += __shfl_xor(sq[r], off, 64);
            }
        }
        #pragma unroll
        for (int r = 0; r < 4; ++r) {
            float mu  = sv[r] * (1.f/64.f);
            float var = sq[r] * (1.f/64.f) - mu*mu;
            float rstd = 1.f / sqrtf(var + EPSF);
            int node = mt*16 + q*4 + r;
            #pragma unroll
            for (int nt2 = 0; nt2 < 4; ++nt2) {
                float o = (v[nt2][r] - mu) * rstd * lwv[nt2] + lbv[nt2];
                smem[node*ZP + nt2*16 + col] = f2bf(o);
            }
        }
    }
    __syncthreads();
    // ---- coalesced write-out: full 128 B line per node ----
    for (int i = tid; i < NN*16; i += 256) {
        int node = i >> 4, c8 = i & 15;
        unsigned long long vv = *(const unsigned long long*)(&smem[node*ZP + c8*4]);
        *(unsigned long long*)(xbase + (size_t)node*SH + c8*4) = vv;
    }
}

// ---------------------------------------------------------------------------
// Head futr+bias: out[row,p] = c0[p] + xfut[row,:192] @ C1   (plain writes,
// runs BEFORE k_head_mfma which atomically accumulates the hist GEMM)
// ---------------------------------------------------------------------------
__global__ __launch_bounds__(192) void k_head_futr(const float* __restrict__ xfut,
        const float* __restrict__ C1, const float* __restrict__ c0,
        float* __restrict__ out) {
    __shared__ float C1l[192*PP];   // 36.8 KB
    __shared__ float xfl[4*192];    // 3 KB
    int tid = threadIdx.x;
    int r0 = blockIdx.x * 4;
    for (int i = tid; i < 192*PP; i += 192) C1l[i] = C1[i];
    for (int i = tid; i < 4*192; i += 192) xfl[i] = xfut[(size_t)r0*192 + i];
    __syncthreads();
    int p = tid % PP, rr = tid / PP;
    float acc = c0[p];
    #pragma unroll 8
    for (int j = 0; j < 192; ++j) acc += xfl[rr*192 + j] * C1l[j*PP + p];
    out[(size_t)(r0 + rr)*PP + p] = acc;
}

// ---------------------------------------------------------------------------
// Head hist GEMM (bf16 MFMA): out[row,p] += X[row,:12288] @ hWT^T
// A-op = X rows straight from global; B-op = hWT (L2-hot). Split-K x8.
// ---------------------------------------------------------------------------
#define KSL 1536
__global__ __launch_bounds__(256) void k_head_mfma(const unsigned short* __restrict__ X,
        const unsigned short* __restrict__ hWT, float* __restrict__ out) {
    int tid = threadIdx.x;
    int lane = tid & 63, w = tid >> 6;
    int col = lane & 15, q = lane >> 4;
    int m0 = blockIdx.x*64 + w*16;
    int k0 = blockIdx.y*KSL;
    const unsigned short* xp = X + (size_t)(m0 + col)*SH + k0 + q*8;
    const unsigned short* wp = hWT + (size_t)col*SH + k0 + q*8;
    f32x4 acc[3];
    #pragma unroll
    for (int nt = 0; nt < 3; ++nt) acc[nt] = (f32x4){0.f,0.f,0.f,0.f};
    #pragma unroll 4
    for (int kk = 0; kk < KSL; kk += 32) {
        bf16x8 a = *(const bf16x8*)(xp + kk);
        #pragma unroll
        for (int nt = 0; nt < 3; ++nt) {
            bf16x8 b = *(const bf16x8*)(wp + (size_t)nt*16*SH + kk);
            acc[nt] = __builtin_amdgcn_mfma_f32_16x16x32_bf16(a, b, acc[nt], 0, 0, 0);
        }
    }
    int orow = m0 + q*4;
    #pragma unroll
    for (int nt = 0; nt < 3; ++nt)
        #pragma unroll
        for (int r = 0; r < 4; ++r)
            atomicAdd(&out[(size_t)(orow + r)*PP + nt*16 + col], acc[nt][r]);
}

// ---------------------------------------------------------------------------
extern "C" void kernel_launch(void* const* d_in, const int* in_sizes, int n_in,
                              void* d_out, int out_size, void* d_ws, size_t ws_size,
                              hipStream_t stream) {
    const float* x     = (const float*)d_in[0];
    const float* xfut  = (const float*)d_in[1];
    const float* adj   = (const float*)d_in[2];
    const float* emb   = (const float*)d_in[3];
    const float* alpha = (const float*)d_in[4];
    const float* inw   = (const float*)d_in[5];
    const float* inb   = (const float*)d_in[6];
    const float* pW    = (const float*)d_in[7];
    const float* pb    = (const float*)d_in[8];
    const float* tW    = (const float*)d_in[9];
    const float* tb    = (const float*)d_in[10];
    const float* gW    = (const float*)d_in[11];
    const float* gb    = (const float*)d_in[12];
    const float* lnw   = (const float*)d_in[13];
    const float* lnb   = (const float*)d_in[14];
    const float* fW    = (const float*)d_in[15];
    const float* fb    = (const float*)d_in[16];
    const float* hW    = (const float*)d_in[17];
    const float* hb    = (const float*)d_in[18];
    float* out = (float*)d_out;

    // Workspace layout (~160 MB): bufX 157.3MB + adjacency/weights ~1.6MB
    unsigned short* bufX = (unsigned short*)d_ws;
    float* Amat = (float*)(bufX + XSZ);
    float* Araw = Amat + NN*NN;
    float* dvec = Araw + NN*NN;
    unsigned short* tWb = (unsigned short*)(dvec + NN);
    unsigned short* Ab  = tWb + NBLK*SS*SS;
    unsigned short* gWT = Ab + NPAD*KPAD;
    unsigned short* hWT = gWT + NBLK*HH*HH;
    float* C1 = (float*)(hWT + (size_t)PP*SH);
    float* c0 = C1 + 192*PP;

    k_adj_row<<<NN, 64, 0, stream>>>(emb, adj, alpha, Araw, dvec);
    k_adj_scale<<<NN, 256, 0, stream>>>(Araw, dvec, Amat);
    k_prep<<<(NBLK*SS*SS + 255)/256, 256, 0, stream>>>(tW, gW, Amat, tWb, Ab, gWT);
    k_prep2<<<((size_t)PP*SH + 255)/256, 256, 0, stream>>>(hW, fW, fb, hb, hWT, C1, c0);
    k_stage0<<<ROWS, 64, 0, stream>>>(x, inw, inb, pW, pb, emb, bufX);

    for (int i = 0; i < NBLK; ++i) {
        k_temporal_mfma<<<ROWS, 256, 0, stream>>>(bufX, tWb + (size_t)i*SS*SS, tb + i*SS);
        k_spatial_fused<<<dim3(SS, BB), 256, 0, stream>>>(bufX, Ab, gWT + (size_t)i*HH*HH,
                                                          gb + i*HH, lnw + i*HH, lnb + i*HH);
    }
    k_head_futr<<<ROWS/4, 192, 0, stream>>>(xfut, C1, c0, out);
    k_head_mfma<<<dim3(ROWS/64, 8), 256, 0, stream>>>(bufX, hWT, out);
}

// Round 10
// 1185.312 us; speedup vs baseline: 1.2490x; 1.0092x over previous
//
#include <hip/hip_runtime.h>
#include <math.h>

// Problem constants
#define BB   32
#define NN   200
#define SS   192
#define FIN  8
#define HH   64
#define PP   48
#define FNN  4
#define KK   10
#define NBLK 3
#define EPSF 1e-5f
#define SH   (SS*HH)               // 12288
#define XSZ  ((size_t)BB*NN*SS*HH) // 78,643,200 elements
#define ROWS (BB*NN)               // 6400
#define NPAD 208                   // node dim padded
#define KPAD 224                   // node contraction padded (7 x 32)

// Swizzled transposed-tile geometry (both temporal and spatial):
//   elem (row, c) at u16 [row*256 + ((((c>>3) ^ ((row>>1)&31))&31)<<3) + (c&7)]
#define XSW   256
// spatial z / As regions
#define ZP    72
#define ASP   40
#define GWP   72
#define ASOFF 16384                // u16 offset of As/gw region
#define ASOFF32 8192               // dword offset
#define SMTOT (16384 + 8320)       // 24704 u16 = 49408 B

typedef __attribute__((ext_vector_type(8))) short bf16x8;
typedef __attribute__((ext_vector_type(4))) float f32x4;

// bf16 <-> f32 helpers on raw ushort storage
__device__ __forceinline__ float bf2f(unsigned short u) {
    union { unsigned int i; float f; } v; v.i = ((unsigned int)u) << 16; return v.f;
}
__device__ __forceinline__ unsigned short f2bf(float f) {
    union { float f; unsigned int i; } v; v.f = f;
    unsigned int r = v.i + 0x7FFFu + ((v.i >> 16) & 1u);   // round-nearest-even
    return (unsigned short)(r >> 16);
}

__device__ __forceinline__ float wave_sum(float v) {
    #pragma unroll
    for (int off = 32; off > 0; off >>= 1) v += __shfl_xor(v, off, 64);
    return v;
}
__device__ __forceinline__ float wave_max(float v) {
    #pragma unroll
    for (int off = 32; off > 0; off >>= 1) v = fmaxf(v, __shfl_xor(v, off, 64));
    return v;
}

// ---------------------------------------------------------------------------
// Adjacency: la = relu(E E^T); top-K mask; softmax; blend with adj; diag=1;
// store un-normalized row + d_r. One wave per row.
// ---------------------------------------------------------------------------
__global__ void k_adj_row(const float* __restrict__ emb, const float* __restrict__ adj,
                          const float* __restrict__ alpha_p,
                          float* __restrict__ Araw, float* __restrict__ dvec) {
    int r = blockIdx.x;
    int lane = threadIdx.x;
    __shared__ float er[HH];
    __shared__ float la[NN];
    __shared__ float tmp[NN];
    __shared__ float keep[NN];
    er[lane] = emb[r*HH + lane];
    __syncthreads();
    for (int j = lane; j < NN; j += 64) {
        float d = 0.f;
        #pragma unroll 8
        for (int h = 0; h < HH; ++h) d += er[h] * emb[j*HH + h];
        float v = fmaxf(d, 0.f);
        la[j] = v; tmp[j] = v; keep[j] = 0.f;
    }
    __syncthreads();
    for (int it = 0; it < KK; ++it) {
        float bv = -1.f; int bi = NN;
        for (int j = lane; j < NN; j += 64) {
            float v = tmp[j];
            if (v > bv) { bv = v; bi = j; }
        }
        #pragma unroll
        for (int off = 32; off > 0; off >>= 1) {
            float ov = __shfl_xor(bv, off, 64);
            int   oi = __shfl_xor(bi, off, 64);
            if (ov > bv || (ov == bv && oi < bi)) { bv = ov; bi = oi; }
        }
        if (lane == 0) { keep[bi] = 1.f; tmp[bi] = -1.f; }
        __syncthreads();
    }
    float mloc = 0.f;
    for (int j = lane; j < NN; j += 64) {
        float v = (keep[j] > 0.f) ? la[j] : 0.f;
        tmp[j] = v;
        mloc = fmaxf(mloc, v);
    }
    float m = wave_max(mloc);
    float sloc = 0.f;
    for (int j = lane; j < NN; j += 64) sloc += expf(tmp[j] - m);
    float ssum = wave_sum(sloc);
    float alpha = alpha_p[0];
    float rloc = 0.f;
    for (int j = lane; j < NN; j += 64) {
        float soft = expf(tmp[j] - m) / ssum;
        float comb = alpha * adj[r*NN + j] + (1.f - alpha) * soft;
        float a = (j == r) ? 1.f : comb;
        Araw[r*NN + j] = a;
        rloc += a;
    }
    float rs = wave_sum(rloc);
    if (lane == 0) dvec[r] = 1.f / sqrtf(fmaxf(rs, 1.f));
}

__global__ void k_adj_scale(const float* __restrict__ Araw, const float* __restrict__ dvec,
                            float* __restrict__ Amat) {
    int r = blockIdx.x, j = threadIdx.x;
    if (j < NN) Amat[r*NN + j] = Araw[r*NN + j] * dvec[r] * dvec[j];
}

// ---------------------------------------------------------------------------
// Prep: cast tW -> bf16; build padded bf16 adjacency (208x224, zeros in pad);
// build transposed bf16 gcn weights gWT[i][n][k] = gW[i][k][n].
// ---------------------------------------------------------------------------
__global__ void k_prep(const float* __restrict__ tW, const float* __restrict__ gW,
                       const float* __restrict__ Amat, unsigned short* __restrict__ tWb,
                       unsigned short* __restrict__ Ab, unsigned short* __restrict__ gWT) {
    int i = blockIdx.x*256 + threadIdx.x;
    if (i < NBLK*SS*SS) tWb[i] = f2bf(tW[i]);
    if (i < NPAD*KPAD) {
        int m = i / KPAD, k = i % KPAD;
        Ab[i] = (m < NN && k < NN) ? f2bf(Amat[m*NN + k]) : (unsigned short)0;
    }
    if (i < NBLK*HH*HH) {
        int blk = i >> 12, r = (i >> 6) & 63, c = i & 63;
        gWT[i] = f2bf(gW[(blk << 12) + c*HH + r]);
    }
}

// ---------------------------------------------------------------------------
// Prep2 (head): hWT[n][k] = bf16(head_W[k][n]) for k < SH;
//   C1[j=p2*4+f][p] = sum_h fW[f,h]*hW[SH+p2*64+h][p]   (futr branch folded)
//   c0[p] = hb[p] + sum_{p2,h} fb[h]*hW[SH+p2*64+h][p]
// ---------------------------------------------------------------------------
__global__ void k_prep2(const float* __restrict__ hW, const float* __restrict__ fW,
                        const float* __restrict__ fb, const float* __restrict__ hb,
                        unsigned short* __restrict__ hWT, float* __restrict__ C1,
                        float* __restrict__ c0) {
    int i = blockIdx.x*256 + threadIdx.x;
    if (i < PP*SH) {
        int n = i / SH, k = i % SH;
        hWT[i] = f2bf(hW[(size_t)k*PP + n]);
    }
    if (i < PP*FNN*PP) {            // 192*48
        int j = i / PP, p = i % PP;
        int p2 = j >> 2, f = j & 3;
        float s = 0.f;
        #pragma unroll 8
        for (int h = 0; h < HH; ++h)
            s += fW[f*HH + h] * hW[(size_t)(SH + p2*HH + h)*PP + p];
        C1[i] = s;
    }
    if (i < PP) {
        float s = hb[i];
        for (int c = 0; c < PP*HH; ++c)
            s += fb[c & 63] * hW[(size_t)(SH + c)*PP + i];
        c0[i] = s;
    }
}

// ---------------------------------------------------------------------------
// Shared temporal MFMA body: xT is the swizzled [t-row? no: row=h][s] tile?
// NOTE: xT here is [h][s]? NO — temporal contracts over s: B[n=h][k=s].
// xT rows are h? WRONG — rows are h for B-frags AND residual: row=h, col=s.
// (kept identical to prior verified structure, just swizzled addressing)
// ---------------------------------------------------------------------------
__device__ __forceinline__ void temporal_mfma_body(const unsigned short* xT,
        unsigned short* __restrict__ xp, const unsigned short* __restrict__ Wb,
        const float* __restrict__ tb, int tid) {
    int lane = tid & 63, w = tid >> 6;
    int col = lane & 15, q = lane >> 4;
    f32x4 acc[3][4];
    #pragma unroll
    for (int tt = 0; tt < 3; ++tt)
        #pragma unroll
        for (int ht = 0; ht < 4; ++ht) acc[tt][ht] = (f32x4){0.f,0.f,0.f,0.f};

    #pragma unroll 2
    for (int k0 = 0; k0 < SS; k0 += 32) {
        bf16x8 a[3], b[4];
        int kc = (k0 >> 3) + q;
        #pragma unroll
        for (int tt = 0; tt < 3; ++tt)
            a[tt] = *(const bf16x8*)(Wb + (size_t)(w*48 + tt*16 + col)*SS + k0 + q*8);
        #pragma unroll
        for (int ht = 0; ht < 4; ++ht) {
            int row = ht*16 + col;
            b[ht] = *(const bf16x8*)(&xT[row*XSW + (((kc ^ ((row>>1)&31)) & 31)<<3)]);
        }
        #pragma unroll
        for (int tt = 0; tt < 3; ++tt)
            #pragma unroll
            for (int ht = 0; ht < 4; ++ht)
                acc[tt][ht] = __builtin_amdgcn_mfma_f32_16x16x32_bf16(a[tt], b[ht], acc[tt][ht], 0, 0, 0);
    }
    #pragma unroll
    for (int tt = 0; tt < 3; ++tt) {
        int t0 = w*48 + tt*16 + q*4;
        float tbv[4];
        #pragma unroll
        for (int r = 0; r < 4; ++r) tbv[r] = tb[t0 + r];
        #pragma unroll
        for (int ht = 0; ht < 4; ++ht) {
            int h = ht*16 + col;
            unsigned long long rr = *(const unsigned long long*)
                (&xT[h*XSW + ((((t0>>3) ^ ((h>>1)&31)) & 31)<<3) + (t0&7)]);
            #pragma unroll
            for (int r = 0; r < 4; ++r) {
                float y = acc[tt][ht][r] + tbv[r];
                // gelu(y) ~= y * sigmoid(2*0.7978845608*(y + 0.044715 y^3))
                float u2 = y * (1.5957691216f + 0.07135481626f*y*y);
                float g = y / (1.f + __expf(-u2));
                xp[(t0 + r)*HH + h] = f2bf(bf2f((unsigned short)(rr >> (16*r))) + g);
            }
        }
    }
}

// ---------------------------------------------------------------------------
// Fused stage0 + temporal block 0: InstanceNorm over S (per b,n,f) -> proj
// (8->64) -> +emb computed straight into the swizzled xT LDS tile, then the
// temporal MFMA body. Saves a full 157 MB X write + read vs separate kernels.
// ---------------------------------------------------------------------------
__global__ __launch_bounds__(256) void k_stage0_temporal(
        const float* __restrict__ x, const float* __restrict__ inw,
        const float* __restrict__ inb, const float* __restrict__ pW,
        const float* __restrict__ pb, const float* __restrict__ emb,
        unsigned short* __restrict__ X, const unsigned short* __restrict__ Wb,
        const float* __restrict__ tb) {
    __shared__ unsigned short xT[HH * XSW];   // 32 KB
    __shared__ float xl[SS*FIN];              // 6 KB
    __shared__ float red[4][2][FIN];
    int bn = blockIdx.x, tid = threadIdx.x;
    int n = bn % NN;
    int lane = tid & 63, w = tid >> 6;
    const float* xin = x + (size_t)bn*SS*FIN;
    for (int i = tid; i < SS*FIN; i += 256) xl[i] = xin[i];
    __syncthreads();
    // stats: thread covers f = tid&7, s-slice = tid>>3 (6 timesteps)
    {
        int f = tid & 7, sl = tid >> 3;
        float s1 = 0.f, s2 = 0.f;
        #pragma unroll
        for (int j = 0; j < 6; ++j) {
            float v = xl[(sl*6 + j)*FIN + f];
            s1 += v; s2 += v*v;
        }
        #pragma unroll
        for (int off = 8; off <= 32; off <<= 1) {
            s1 += __shfl_xor(s1, off, 64);
            s2 += __shfl_xor(s2, off, 64);
        }
        if (lane < FIN) { red[w][0][lane] = s1; red[w][1][lane] = s2; }
    }
    __syncthreads();
    int h = lane;
    float sp8[FIN];
    float cst = pb[h] + emb[n*HH + h];
    #pragma unroll
    for (int f = 0; f < FIN; ++f) {
        float a  = red[0][0][f] + red[1][0][f] + red[2][0][f] + red[3][0][f];
        float b2 = red[0][1][f] + red[1][1][f] + red[2][1][f] + red[3][1][f];
        float mu  = a * (1.f/SS);
        float var = b2 * (1.f/SS) - mu*mu;
        float sc  = inw[f] / sqrtf(var + EPSF);
        float pw  = pW[f*HH + h];
        sp8[f] = sc * pw;
        cst += (inb[f] - mu*sc) * pw;
    }
    int key = (h >> 1) & 31;
    for (int j4 = 0; j4 < 12; ++j4) {
        int s0 = w*48 + j4*4;
        unsigned long long pk = 0;
        #pragma unroll
        for (int r = 0; r < 4; ++r) {
            float acc = cst;
            #pragma unroll
            for (int f = 0; f < FIN; ++f) acc += xl[(s0 + r)*FIN + f] * sp8[f];
            pk |= (unsigned long long)f2bf(acc) << (16*r);
        }
        *(unsigned long long*)(&xT[h*XSW + ((((s0>>3) ^ key) & 31)<<3) + (s0&7)]) = pk;
    }
    __syncthreads();
    temporal_mfma_body(xT, X + (size_t)bn*SH, Wb, tb, tid);
}

// ---------------------------------------------------------------------------
// Temporal MFMA (IN-PLACE), iterations 1..: stage X row into swizzled xT via
// dword-pair micro-transpose (4-way max bank aliasing), then shared body.
// ---------------------------------------------------------------------------
__global__ __launch_bounds__(256) void k_temporal_mfma(unsigned short* __restrict__ X,
        const unsigned short* __restrict__ Wb, const float* __restrict__ tb) {
    __shared__ unsigned short xT[HH * XSW];   // 32 KB
    unsigned int* sm32 = (unsigned int*)xT;
    int bn = blockIdx.x, tid = threadIdx.x;
    unsigned short* xp = X + (size_t)bn*SH;
    const unsigned int* xp32 = (const unsigned int*)xp;
    // element (s, h) -> xT row h, col s (swizzled). Process s-pairs:
    for (int i = tid; i < 96*32; i += 256) {
        int sp = i >> 5, hp = i & 31;
        unsigned int u0 = xp32[(2*sp)*32 + hp];
        unsigned int u1 = xp32[(2*sp+1)*32 + hp];
        unsigned int lo = (u0 & 0xffffu) | (u1 << 16);          // h=2hp  @ s,s+1
        unsigned int hi = (u0 >> 16) | (u1 & 0xffff0000u);      // h=2hp+1
        int swz = ((((sp>>2) ^ hp) & 31)<<2) + (sp&3);
        sm32[(2*hp)*128 + swz]   = lo;    // key for rows 2hp,2hp+1 is hp
        sm32[(2*hp+1)*128 + swz] = hi;
    }
    __syncthreads();
    temporal_mfma_body(xT, xp, Wb, tb, tid);
}

// ---------------------------------------------------------------------------
// Fused spatial (IN-PLACE on X), block = (s', b), 256 threads / 4 waves:
//   z[node,h] = sum_n A[node,n] x[b,n,s',h]        (MFMA1, K=224)
//   y[node,h'] = z[node,:] @ gcn_W                 (MFMA2, K=64)
//   x = LN_h'( x + y + gb ) * ln_w + ln_b
// (row>>1) swizzle key: staging 4-way max; As K-slices LDS-staged w/ register
// prefetch; LN output bounced through LDS, full-line writes.
// ---------------------------------------------------------------------------
__global__ __launch_bounds__(256, 3) void k_spatial_fused(unsigned short* __restrict__ X,
        const unsigned short* __restrict__ Ab, const unsigned short* __restrict__ gWT,
        const float* __restrict__ gb, const float* __restrict__ lnw,
        const float* __restrict__ lnb) {
    __shared__ unsigned short smem[SMTOT];       // 49.4 KB
    unsigned int* sm32 = (unsigned int*)smem;
    int sp = blockIdx.x, b = blockIdx.y, tid = threadIdx.x;
    unsigned short* xbase = X + (size_t)b*NN*SH + sp*HH;
    const unsigned int* xp32 = (const unsigned int*)xbase;
    const unsigned int* Ab32 = (const unsigned int*)Ab;
    const unsigned int* gW32 = (const unsigned int*)gWT;

    // stage xT: elem (h, n) -> row h, col n (swizzled, key = (h>>1)&31)
    for (int i = tid; i < 100*32; i += 256) {
        int np = i >> 5, dd = i & 31;            // node pair, h-dword
        unsigned int u0 = xp32[(size_t)(2*np)*(SH/2) + dd];
        unsigned int u1 = xp32[(size_t)(2*np+1)*(SH/2) + dd];
        unsigned int lo = (u0 & 0xffffu) | (u1 << 16);          // h=2dd
        unsigned int hi = (u0 >> 16) | (u1 & 0xffff0000u);      // h=2dd+1
        int swz = ((((np>>2) ^ dd) & 31)<<2) + (np&3);          // key = dd
        sm32[(2*dd)*128 + swz]   = lo;
        sm32[(2*dd+1)*128 + swz] = hi;
    }
    // zero-pad node cols 200..223 (dword cols 100..111)
    for (int i = tid; i < 64*12; i += 256) {
        int r = i / 12, kdw = 100 + (i % 12);
        sm32[r*128 + ((((kdw>>2) ^ ((r>>1)&31)) & 31)<<2) + (kdw&3)] = 0;
    }
    // stage adjacency K-slice 0 (Ab[node][0..31])
    for (int i = tid; i < NPAD*16; i += 256) {
        int node = i >> 4, dw = i & 15;
        sm32[ASOFF32 + node*20 + dw] = Ab32[node*112 + dw];
    }
    __syncthreads();

    int lane = tid & 63, w = tid >> 6;
    int col = lane & 15, q = lane >> 4;
    int arow = w*16 + col;                       // xT row for MFMA1 A-frag
    int akey = (arow >> 1) & 31;

    // ---- MFMA1 with As prefetch pipeline ----
    f32x4 acc1[13];
    #pragma unroll
    for (int nt = 0; nt < 13; ++nt) acc1[nt] = (f32x4){0.f,0.f,0.f,0.f};
    unsigned int pf[13];
    for (int step = 0; step < 7; ++step) {
        if (step < 6) {
            int kb = (step + 1) * 16;            // dword offset into Ab row
            #pragma unroll
            for (int it = 0; it < 13; ++it) {
                int idx = tid + it*256;
                pf[it] = Ab32[(idx>>4)*112 + kb + (idx&15)];
            }
        }
        int cb = step*4;                          // chunk base = k0>>3
        bf16x8 a = *(const bf16x8*)(&smem[arow*XSW + ((((cb + q) ^ akey) & 31)<<3)]);
        #pragma unroll
        for (int nt = 0; nt < 13; ++nt) {
            bf16x8 bb = *(const bf16x8*)(&smem[ASOFF + (nt*16 + col)*ASP + q*8]);
            acc1[nt] = __builtin_amdgcn_mfma_f32_16x16x32_bf16(a, bb, acc1[nt], 0, 0, 0);
        }
        __syncthreads();                          // As consumed by all waves
        if (step < 6) {
            #pragma unroll
            for (int it = 0; it < 13; ++it) {
                int idx = tid + it*256;
                sm32[ASOFF32 + (idx>>4)*20 + (idx&15)] = pf[it];
            }
        }
        __syncthreads();                          // As slice ready
    }

    // ---- hoist residual x[node][h'] from xT before overwrite ----
    unsigned long long res[4][4];
    #pragma unroll
    for (int j = 0; j < 4; ++j) {
        int mt = w + 4*j;
        if (mt < 13) {
            #pragma unroll
            for (int nt2 = 0; nt2 < 4; ++nt2) {
                int rr = nt2*16 + col;            // xT row (h')
                int k  = mt*16 + q*4;             // node col
                res[j][nt2] = *(const unsigned long long*)
                    (&smem[rr*XSW + ((((k>>3) ^ ((rr>>1)&31)) & 31)<<3) + (k&7)]);
            }
        }
    }
    __syncthreads();
    // ---- write z (union over xT region) + stage gcn_W into As region ----
    #pragma unroll
    for (int nt = 0; nt < 13; ++nt) {
        unsigned long long pk =
              (unsigned long long)f2bf(acc1[nt][0])
            | ((unsigned long long)f2bf(acc1[nt][1]) << 16)
            | ((unsigned long long)f2bf(acc1[nt][2]) << 32)
            | ((unsigned long long)f2bf(acc1[nt][3]) << 48);
        *(unsigned long long*)(&smem[(nt*16 + col)*ZP + w*16 + q*4]) = pk;
    }
    for (int i = tid; i < 64*32; i += 256) {
        int n2 = i >> 5, kdw = i & 31;
        sm32[ASOFF32 + n2*36 + kdw] = gW32[n2*32 + kdw];
    }
    __syncthreads();

    // ---- MFMA2 + LN; results written back into z region (own rows) ----
    float gbv[4], lwv[4], lbv[4];
    #pragma unroll
    for (int nt2 = 0; nt2 < 4; ++nt2) {
        int h = nt2*16 + col;
        gbv[nt2] = gb[h]; lwv[nt2] = lnw[h]; lbv[nt2] = lnb[h];
    }
    #pragma unroll
    for (int j = 0; j < 4; ++j) {
        int mt = w + 4*j;
        if (mt >= 13) break;
        f32x4 acc2[4];
        #pragma unroll
        for (int nt2 = 0; nt2 < 4; ++nt2) acc2[nt2] = (f32x4){0.f,0.f,0.f,0.f};
        #pragma unroll
        for (int k0 = 0; k0 < HH; k0 += 32) {
            bf16x8 a = *(const bf16x8*)(&smem[(mt*16 + col)*ZP + k0 + q*8]);
            #pragma unroll
            for (int nt2 = 0; nt2 < 4; ++nt2) {
                bf16x8 bw = *(const bf16x8*)(&smem[ASOFF + (nt2*16 + col)*GWP + k0 + q*8]);
                acc2[nt2] = __builtin_amdgcn_mfma_f32_16x16x32_bf16(a, bw, acc2[nt2], 0, 0, 0);
            }
        }
        float v[4][4];
        float sv[4] = {0.f,0.f,0.f,0.f}, sq[4] = {0.f,0.f,0.f,0.f};
        #pragma unroll
        for (int nt2 = 0; nt2 < 4; ++nt2) {
            unsigned long long rr = res[j][nt2];
            #pragma unroll
            for (int r = 0; r < 4; ++r) {
                float t = acc2[nt2][r] + bf2f((unsigned short)(rr >> (16*r))) + gbv[nt2];
                v[nt2][r] = t; sv[r] += t; sq[r] += t*t;
            }
        }
        #pragma unroll
        for (int r = 0; r < 4; ++r) {
            #pragma unroll
            for (int off = 1; off < 16; off <<= 1) {
                sv[r] += __shfl_xor(sv[r], off, 64);
                sq[r] += __shfl_xor(sq[r], off, 64);
            }
        }
        #pragma unroll
        for (int r = 0; r < 4; ++r) {
            float mu  = sv[r] * (1.f/64.f);
            float var = sq[r] * (1.f/64.f) - mu*mu;
            float rstd = 1.f / sqrtf(var + EPSF);
            int node = mt*16 + q*4 + r;
            #pragma unroll
            for (int nt2 = 0; nt2 < 4; ++nt2) {
                float o = (v[nt2][r] - mu) * rstd * lwv[nt2] + lbv[nt2];
                smem[node*ZP + nt2*16 + col] = f2bf(o);
            }
        }
    }
    __syncthreads();
    // ---- coalesced write-out: full 128 B line per node (b128 chunks) ----
    for (int i = tid; i < NN*8; i += 256) {
        int node = i >> 3, c16 = i & 7;
        uint4 vv = *(const uint4*)(&smem[node*ZP + c16*8]);
        *(uint4*)(xbase + (size_t)node*SH + c16*8) = vv;
    }
}

// ---------------------------------------------------------------------------
// Head futr+bias: out[row,p] = c0[p] + xfut[row,:192] @ C1   (plain writes,
// runs BEFORE k_head_mfma which atomically accumulates the hist GEMM)
// ---------------------------------------------------------------------------
__global__ __launch_bounds__(192) void k_head_futr(const float* __restrict__ xfut,
        const float* __restrict__ C1, const float* __restrict__ c0,
        float* __restrict__ out) {
    __shared__ float C1l[192*PP];   // 36.8 KB
    __shared__ float xfl[4*192];    // 3 KB
    int tid = threadIdx.x;
    int r0 = blockIdx.x * 4;
    for (int i = tid; i < 192*PP; i += 192) C1l[i] = C1[i];
    for (int i = tid; i < 4*192; i += 192) xfl[i] = xfut[(size_t)r0*192 + i];
    __syncthreads();
    int p = tid % PP, rr = tid / PP;
    float acc = c0[p];
    #pragma unroll 8
    for (int j = 0; j < 192; ++j) acc += xfl[rr*192 + j] * C1l[j*PP + p];
    out[(size_t)(r0 + rr)*PP + p] = acc;
}

// ---------------------------------------------------------------------------
// Head hist GEMM (bf16 MFMA): out[row,p] += X[row,:12288] @ hWT^T
// A-op = X rows straight from global; B-op = hWT (L2-hot). Split-K x8.
// ---------------------------------------------------------------------------
#define KSL 1536
__global__ __launch_bounds__(256) void k_head_mfma(const unsigned short* __restrict__ X,
        const unsigned short* __restrict__ hWT, float* __restrict__ out) {
    int tid = threadIdx.x;
    int lane = tid & 63, w = tid >> 6;
    int col = lane & 15, q = lane >> 4;
    int m0 = blockIdx.x*64 + w*16;
    int k0 = blockIdx.y*KSL;
    const unsigned short* xp = X + (size_t)(m0 + col)*SH + k0 + q*8;
    const unsigned short* wp = hWT + (size_t)col*SH + k0 + q*8;
    f32x4 acc[3];
    #pragma unroll
    for (int nt = 0; nt < 3; ++nt) acc[nt] = (f32x4){0.f,0.f,0.f,0.f};
    #pragma unroll 4
    for (int kk = 0; kk < KSL; kk += 32) {
        bf16x8 a = *(const bf16x8*)(xp + kk);
        #pragma unroll
        for (int nt = 0; nt < 3; ++nt) {
            bf16x8 b = *(const bf16x8*)(wp + (size_t)nt*16*SH + kk);
            acc[nt] = __builtin_amdgcn_mfma_f32_16x16x32_bf16(a, b, acc[nt], 0, 0, 0);
        }
    }
    int orow = m0 + q*4;
    #pragma unroll
    for (int nt = 0; nt < 3; ++nt)
        #pragma unroll
        for (int r = 0; r < 4; ++r)
            atomicAdd(&out[(size_t)(orow + r)*PP + nt*16 + col], acc[nt][r]);
}

// ---------------------------------------------------------------------------
extern "C" void kernel_launch(void* const* d_in, const int* in_sizes, int n_in,
                              void* d_out, int out_size, void* d_ws, size_t ws_size,
                              hipStream_t stream) {
    const float* x     = (const float*)d_in[0];
    const float* xfut  = (const float*)d_in[1];
    const float* adj   = (const float*)d_in[2];
    const float* emb   = (const float*)d_in[3];
    const float* alpha = (const float*)d_in[4];
    const float* inw   = (const float*)d_in[5];
    const float* inb   = (const float*)d_in[6];
    const float* pW    = (const float*)d_in[7];
    const float* pb    = (const float*)d_in[8];
    const float* tW    = (const float*)d_in[9];
    const float* tb    = (const float*)d_in[10];
    const float* gW    = (const float*)d_in[11];
    const float* gb    = (const float*)d_in[12];
    const float* lnw   = (const float*)d_in[13];
    const float* lnb   = (const float*)d_in[14];
    const float* fW    = (const float*)d_in[15];
    const float* fb    = (const float*)d_in[16];
    const float* hW    = (const float*)d_in[17];
    const float* hb    = (const float*)d_in[18];
    float* out = (float*)d_out;

    // Workspace layout (~160 MB): bufX 157.3MB + adjacency/weights ~1.6MB
    unsigned short* bufX = (unsigned short*)d_ws;
    float* Amat = (float*)(bufX + XSZ);
    float* Araw = Amat + NN*NN;
    float* dvec = Araw + NN*NN;
    unsigned short* tWb = (unsigned short*)(dvec + NN);
    unsigned short* Ab  = tWb + NBLK*SS*SS;
    unsigned short* gWT = Ab + NPAD*KPAD;
    unsigned short* hWT = gWT + NBLK*HH*HH;
    float* C1 = (float*)(hWT + (size_t)PP*SH);
    float* c0 = C1 + 192*PP;

    k_adj_row<<<NN, 64, 0, stream>>>(emb, adj, alpha, Araw, dvec);
    k_adj_scale<<<NN, 256, 0, stream>>>(Araw, dvec, Amat);
    k_prep<<<(NBLK*SS*SS + 255)/256, 256, 0, stream>>>(tW, gW, Amat, tWb, Ab, gWT);
    k_prep2<<<((size_t)PP*SH + 255)/256, 256, 0, stream>>>(hW, fW, fb, hb, hWT, C1, c0);

    // fused stage0 + temporal block 0
    k_stage0_temporal<<<ROWS, 256, 0, stream>>>(x, inw, inb, pW, pb, emb, bufX, tWb, tb);
    k_spatial_fused<<<dim3(SS, BB), 256, 0, stream>>>(bufX, Ab, gWT, gb, lnw, lnb);
    for (int i = 1; i < NBLK; ++i) {
        k_temporal_mfma<<<ROWS, 256, 0, stream>>>(bufX, tWb + (size_t)i*SS*SS, tb + i*SS);
        k_spatial_fused<<<dim3(SS, BB), 256, 0, stream>>>(bufX, Ab, gWT + (size_t)i*HH*HH,
                                                          gb + i*HH, lnw + i*HH, lnb + i*HH);
    }
    k_head_futr<<<ROWS/4, 192, 0, stream>>>(xfut, C1, c0, out);
    k_head_mfma<<<dim3(ROWS/64, 8), 256, 0, stream>>>(bufX, hWT, out);
}

// Round 11
// 1163.260 us; speedup vs baseline: 1.2726x; 1.0190x over previous
//
#include <hip/hip_runtime.h>
#include <math.h>

// Problem constants
#define BB   32
#define NN   200
#define SS   192
#define FIN  8
#define HH   64
#define PP   48
#define FNN  4
#define KK   10
#define NBLK 3
#define EPSF 1e-5f
#define SH   (SS*HH)               // 12288
#define XSZ  ((size_t)BB*NN*SS*HH) // 78,643,200 elements
#define ROWS (BB*NN)               // 6400
#define NPAD 208                   // node dim padded
#define KPAD 224                   // node contraction padded (7 x 32)

// Swizzled transposed-tile geometry (both temporal and spatial):
//   elem (row, c) at u16 [row*256 + ((((c>>3) ^ ((row>>1)&31))&31)<<3) + (c&7)]
#define XSW   256
// spatial z / As regions
#define ZP    72
#define ASP   40
#define GWP   72
#define ASOFF 16384                // u16 offset of As/gw region
#define ASOFF32 8192               // dword offset
#define SMTOT (16384 + 8320)       // 24704 u16 = 49408 B

typedef __attribute__((ext_vector_type(8))) short bf16x8;
typedef __attribute__((ext_vector_type(4))) float f32x4;

// bf16 <-> f32 helpers on raw ushort storage
__device__ __forceinline__ float bf2f(unsigned short u) {
    union { unsigned int i; float f; } v; v.i = ((unsigned int)u) << 16; return v.f;
}
__device__ __forceinline__ unsigned short f2bf(float f) {
    union { float f; unsigned int i; } v; v.f = f;
    unsigned int r = v.i + 0x7FFFu + ((v.i >> 16) & 1u);   // round-nearest-even
    return (unsigned short)(r >> 16);
}

__device__ __forceinline__ float wave_sum(float v) {
    #pragma unroll
    for (int off = 32; off > 0; off >>= 1) v += __shfl_xor(v, off, 64);
    return v;
}
__device__ __forceinline__ float wave_max(float v) {
    #pragma unroll
    for (int off = 32; off > 0; off >>= 1) v = fmaxf(v, __shfl_xor(v, off, 64));
    return v;
}

// ---------------------------------------------------------------------------
// Adjacency: la = relu(E E^T); top-K mask; softmax; blend with adj; diag=1;
// store un-normalized row + d_r. One wave per row.
// ---------------------------------------------------------------------------
__global__ void k_adj_row(const float* __restrict__ emb, const float* __restrict__ adj,
                          const float* __restrict__ alpha_p,
                          float* __restrict__ Araw, float* __restrict__ dvec) {
    int r = blockIdx.x;
    int lane = threadIdx.x;
    __shared__ float er[HH];
    __shared__ float la[NN];
    __shared__ float tmp[NN];
    __shared__ float keep[NN];
    er[lane] = emb[r*HH + lane];
    __syncthreads();
    for (int j = lane; j < NN; j += 64) {
        float d = 0.f;
        #pragma unroll 8
        for (int h = 0; h < HH; ++h) d += er[h] * emb[j*HH + h];
        float v = fmaxf(d, 0.f);
        la[j] = v; tmp[j] = v; keep[j] = 0.f;
    }
    __syncthreads();
    for (int it = 0; it < KK; ++it) {
        float bv = -1.f; int bi = NN;
        for (int j = lane; j < NN; j += 64) {
            float v = tmp[j];
            if (v > bv) { bv = v; bi = j; }
        }
        #pragma unroll
        for (int off = 32; off > 0; off >>= 1) {
            float ov = __shfl_xor(bv, off, 64);
            int   oi = __shfl_xor(bi, off, 64);
            if (ov > bv || (ov == bv && oi < bi)) { bv = ov; bi = oi; }
        }
        if (lane == 0) { keep[bi] = 1.f; tmp[bi] = -1.f; }
        __syncthreads();
    }
    float mloc = 0.f;
    for (int j = lane; j < NN; j += 64) {
        float v = (keep[j] > 0.f) ? la[j] : 0.f;
        tmp[j] = v;
        mloc = fmaxf(mloc, v);
    }
    float m = wave_max(mloc);
    float sloc = 0.f;
    for (int j = lane; j < NN; j += 64) sloc += expf(tmp[j] - m);
    float ssum = wave_sum(sloc);
    float alpha = alpha_p[0];
    float rloc = 0.f;
    for (int j = lane; j < NN; j += 64) {
        float soft = expf(tmp[j] - m) / ssum;
        float comb = alpha * adj[r*NN + j] + (1.f - alpha) * soft;
        float a = (j == r) ? 1.f : comb;
        Araw[r*NN + j] = a;
        rloc += a;
    }
    float rs = wave_sum(rloc);
    if (lane == 0) dvec[r] = 1.f / sqrtf(fmaxf(rs, 1.f));
}

__global__ void k_adj_scale(const float* __restrict__ Araw, const float* __restrict__ dvec,
                            float* __restrict__ Amat) {
    int r = blockIdx.x, j = threadIdx.x;
    if (j < NN) Amat[r*NN + j] = Araw[r*NN + j] * dvec[r] * dvec[j];
}

// ---------------------------------------------------------------------------
// Prep: cast tW -> bf16; build padded bf16 adjacency (208x224, zeros in pad);
// build transposed bf16 gcn weights gWT[i][n][k] = gW[i][k][n].
// ---------------------------------------------------------------------------
__global__ void k_prep(const float* __restrict__ tW, const float* __restrict__ gW,
                       const float* __restrict__ Amat, unsigned short* __restrict__ tWb,
                       unsigned short* __restrict__ Ab, unsigned short* __restrict__ gWT) {
    int i = blockIdx.x*256 + threadIdx.x;
    if (i < NBLK*SS*SS) tWb[i] = f2bf(tW[i]);
    if (i < NPAD*KPAD) {
        int m = i / KPAD, k = i % KPAD;
        Ab[i] = (m < NN && k < NN) ? f2bf(Amat[m*NN + k]) : (unsigned short)0;
    }
    if (i < NBLK*HH*HH) {
        int blk = i >> 12, r = (i >> 6) & 63, c = i & 63;
        gWT[i] = f2bf(gW[(blk << 12) + c*HH + r]);
    }
}

// ---------------------------------------------------------------------------
// Prep2 (head): hWT[n][k] = bf16(head_W[k][n]) for k < SH;
//   C1[j=p2*4+f][p] = sum_h fW[f,h]*hW[SH+p2*64+h][p]   (futr branch folded)
//   c0[p] = hb[p] + sum_{p2,h} fb[h]*hW[SH+p2*64+h][p]
// ---------------------------------------------------------------------------
__global__ void k_prep2(const float* __restrict__ hW, const float* __restrict__ fW,
                        const float* __restrict__ fb, const float* __restrict__ hb,
                        unsigned short* __restrict__ hWT, float* __restrict__ C1,
                        float* __restrict__ c0) {
    int i = blockIdx.x*256 + threadIdx.x;
    if (i < PP*SH) {
        int n = i / SH, k = i % SH;
        hWT[i] = f2bf(hW[(size_t)k*PP + n]);
    }
    if (i < PP*FNN*PP) {            // 192*48
        int j = i / PP, p = i % PP;
        int p2 = j >> 2, f = j & 3;
        float s = 0.f;
        #pragma unroll 8
        for (int h = 0; h < HH; ++h)
            s += fW[f*HH + h] * hW[(size_t)(SH + p2*HH + h)*PP + p];
        C1[i] = s;
    }
    if (i < PP) {
        float s = hb[i];
        for (int c = 0; c < PP*HH; ++c)
            s += fb[c & 63] * hW[(size_t)(SH + c)*PP + i];
        c0[i] = s;
    }
}

// ---------------------------------------------------------------------------
// Shared temporal MFMA body: xT = swizzled tile, row = h, col = s.
// ---------------------------------------------------------------------------
__device__ __forceinline__ void temporal_mfma_body(const unsigned short* xT,
        unsigned short* __restrict__ xp, const unsigned short* __restrict__ Wb,
        const float* __restrict__ tb, int tid) {
    int lane = tid & 63, w = tid >> 6;
    int col = lane & 15, q = lane >> 4;
    f32x4 acc[3][4];
    #pragma unroll
    for (int tt = 0; tt < 3; ++tt)
        #pragma unroll
        for (int ht = 0; ht < 4; ++ht) acc[tt][ht] = (f32x4){0.f,0.f,0.f,0.f};

    #pragma unroll 2
    for (int k0 = 0; k0 < SS; k0 += 32) {
        bf16x8 a[3], b[4];
        int kc = (k0 >> 3) + q;
        #pragma unroll
        for (int tt = 0; tt < 3; ++tt)
            a[tt] = *(const bf16x8*)(Wb + (size_t)(w*48 + tt*16 + col)*SS + k0 + q*8);
        #pragma unroll
        for (int ht = 0; ht < 4; ++ht) {
            int row = ht*16 + col;
            b[ht] = *(const bf16x8*)(&xT[row*XSW + (((kc ^ ((row>>1)&31)) & 31)<<3)]);
        }
        #pragma unroll
        for (int tt = 0; tt < 3; ++tt)
            #pragma unroll
            for (int ht = 0; ht < 4; ++ht)
                acc[tt][ht] = __builtin_amdgcn_mfma_f32_16x16x32_bf16(a[tt], b[ht], acc[tt][ht], 0, 0, 0);
    }
    #pragma unroll
    for (int tt = 0; tt < 3; ++tt) {
        int t0 = w*48 + tt*16 + q*4;
        float tbv[4];
        #pragma unroll
        for (int r = 0; r < 4; ++r) tbv[r] = tb[t0 + r];
        #pragma unroll
        for (int ht = 0; ht < 4; ++ht) {
            int h = ht*16 + col;
            unsigned long long rr = *(const unsigned long long*)
                (&xT[h*XSW + ((((t0>>3) ^ ((h>>1)&31)) & 31)<<3) + (t0&7)]);
            #pragma unroll
            for (int r = 0; r < 4; ++r) {
                float y = acc[tt][ht][r] + tbv[r];
                // gelu(y) ~= y * sigmoid(2*0.7978845608*(y + 0.044715 y^3))
                float u2 = y * (1.5957691216f + 0.07135481626f*y*y);
                float g = y / (1.f + __expf(-u2));
                xp[(t0 + r)*HH + h] = f2bf(bf2f((unsigned short)(rr >> (16*r))) + g);
            }
        }
    }
}

// ---------------------------------------------------------------------------
// Fused stage0 + temporal block 0: InstanceNorm over S (per b,n,f) -> proj
// (8->64) -> +emb computed straight into the swizzled xT LDS tile, then the
// temporal MFMA body. Saves a full 157 MB X write + read vs separate kernels.
// ---------------------------------------------------------------------------
__global__ __launch_bounds__(256) void k_stage0_temporal(
        const float* __restrict__ x, const float* __restrict__ inw,
        const float* __restrict__ inb, const float* __restrict__ pW,
        const float* __restrict__ pb, const float* __restrict__ emb,
        unsigned short* __restrict__ X, const unsigned short* __restrict__ Wb,
        const float* __restrict__ tb) {
    __shared__ unsigned short xT[HH * XSW];   // 32 KB
    __shared__ float xl[SS*FIN];              // 6 KB
    __shared__ float red[4][2][FIN];
    int bn = blockIdx.x, tid = threadIdx.x;
    int n = bn % NN;
    int lane = tid & 63, w = tid >> 6;
    const float* xin = x + (size_t)bn*SS*FIN;
    for (int i = tid; i < SS*FIN; i += 256) xl[i] = xin[i];
    __syncthreads();
    // stats: thread covers f = tid&7, s-slice = tid>>3 (6 timesteps)
    {
        int f = tid & 7, sl = tid >> 3;
        float s1 = 0.f, s2 = 0.f;
        #pragma unroll
        for (int j = 0; j < 6; ++j) {
            float v = xl[(sl*6 + j)*FIN + f];
            s1 += v; s2 += v*v;
        }
        #pragma unroll
        for (int off = 8; off <= 32; off <<= 1) {
            s1 += __shfl_xor(s1, off, 64);
            s2 += __shfl_xor(s2, off, 64);
        }
        if (lane < FIN) { red[w][0][lane] = s1; red[w][1][lane] = s2; }
    }
    __syncthreads();
    int h = lane;
    float sp8[FIN];
    float cst = pb[h] + emb[n*HH + h];
    #pragma unroll
    for (int f = 0; f < FIN; ++f) {
        float a  = red[0][0][f] + red[1][0][f] + red[2][0][f] + red[3][0][f];
        float b2 = red[0][1][f] + red[1][1][f] + red[2][1][f] + red[3][1][f];
        float mu  = a * (1.f/SS);
        float var = b2 * (1.f/SS) - mu*mu;
        float sc  = inw[f] / sqrtf(var + EPSF);
        float pw  = pW[f*HH + h];
        sp8[f] = sc * pw;
        cst += (inb[f] - mu*sc) * pw;
    }
    int key = (h >> 1) & 31;
    for (int j4 = 0; j4 < 12; ++j4) {
        int s0 = w*48 + j4*4;
        unsigned long long pk = 0;
        #pragma unroll
        for (int r = 0; r < 4; ++r) {
            float acc = cst;
            #pragma unroll
            for (int f = 0; f < FIN; ++f) acc += xl[(s0 + r)*FIN + f] * sp8[f];
            pk |= (unsigned long long)f2bf(acc) << (16*r);
        }
        *(unsigned long long*)(&xT[h*XSW + ((((s0>>3) ^ key) & 31)<<3) + (s0&7)]) = pk;
    }
    __syncthreads();
    temporal_mfma_body(xT, X + (size_t)bn*SH, Wb, tb, tid);
}

// ---------------------------------------------------------------------------
// Temporal MFMA (IN-PLACE), iterations 1..: stage X row into swizzled xT via
// dword-pair micro-transpose, then shared body.
// ---------------------------------------------------------------------------
__global__ __launch_bounds__(256) void k_temporal_mfma(unsigned short* __restrict__ X,
        const unsigned short* __restrict__ Wb, const float* __restrict__ tb) {
    __shared__ unsigned short xT[HH * XSW];   // 32 KB
    unsigned int* sm32 = (unsigned int*)xT;
    int bn = blockIdx.x, tid = threadIdx.x;
    unsigned short* xp = X + (size_t)bn*SH;
    const unsigned int* xp32 = (const unsigned int*)xp;
    for (int i = tid; i < 96*32; i += 256) {
        int sp = i >> 5, hp = i & 31;
        unsigned int u0 = xp32[(2*sp)*32 + hp];
        unsigned int u1 = xp32[(2*sp+1)*32 + hp];
        unsigned int lo = (u0 & 0xffffu) | (u1 << 16);          // h=2hp  @ s,s+1
        unsigned int hi = (u0 >> 16) | (u1 & 0xffff0000u);      // h=2hp+1
        int swz = ((((sp>>2) ^ hp) & 31)<<2) + (sp&3);
        sm32[(2*hp)*128 + swz]   = lo;
        sm32[(2*hp+1)*128 + swz] = hi;
    }
    __syncthreads();
    temporal_mfma_body(xT, xp, Wb, tb, tid);
}

// ---------------------------------------------------------------------------
// Fused spatial (IN-PLACE on X), block = (s', b), 512 threads / 8 waves:
//   z[node,h] = sum_n A[node,n] x[b,n,s',h]        (MFMA1, K=224)
//   y[node,h'] = z[node,:] @ gcn_W                 (MFMA2, K=64)
//   x = LN_h'( x + y + gb ) * ln_w + ln_b
// R10: 8 waves/block — waves split the 13 node-tiles (7/6) in MFMA1 and the
// mt-tiles in MFMA2, halving the per-block serial chain; 24 waves/CU.
// ---------------------------------------------------------------------------
__global__ __launch_bounds__(512, 6) void k_spatial_fused(unsigned short* __restrict__ X,
        const unsigned short* __restrict__ Ab, const unsigned short* __restrict__ gWT,
        const float* __restrict__ gb, const float* __restrict__ lnw,
        const float* __restrict__ lnb) {
    __shared__ unsigned short smem[SMTOT];       // 49.4 KB
    unsigned int* sm32 = (unsigned int*)smem;
    int sp = blockIdx.x, b = blockIdx.y, tid = threadIdx.x;
    unsigned short* xbase = X + (size_t)b*NN*SH + sp*HH;
    const unsigned int* xp32 = (const unsigned int*)xbase;
    const unsigned int* Ab32 = (const unsigned int*)Ab;
    const unsigned int* gW32 = (const unsigned int*)gWT;

    // stage xT: elem (h, n) -> row h, col n (swizzled, key = (h>>1)&31)
    for (int i = tid; i < 100*32; i += 512) {
        int np = i >> 5, dd = i & 31;            // node pair, h-dword
        unsigned int u0 = xp32[(size_t)(2*np)*(SH/2) + dd];
        unsigned int u1 = xp32[(size_t)(2*np+1)*(SH/2) + dd];
        unsigned int lo = (u0 & 0xffffu) | (u1 << 16);          // h=2dd
        unsigned int hi = (u0 >> 16) | (u1 & 0xffff0000u);      // h=2dd+1
        int swz = ((((np>>2) ^ dd) & 31)<<2) + (np&3);          // key = dd
        sm32[(2*dd)*128 + swz]   = lo;
        sm32[(2*dd+1)*128 + swz] = hi;
    }
    // zero-pad node cols 200..223 (dword cols 100..111)
    for (int i = tid; i < 64*12; i += 512) {
        int r = i / 12, kdw = 100 + (i % 12);
        sm32[r*128 + ((((kdw>>2) ^ ((r>>1)&31)) & 31)<<2) + (kdw&3)] = 0;
    }
    // stage adjacency K-slice 0 (Ab[node][0..31])
    for (int i = tid; i < NPAD*16; i += 512) {
        int node = i >> 4, dw = i & 15;
        sm32[ASOFF32 + node*20 + dw] = Ab32[node*112 + dw];
    }
    __syncthreads();

    int lane = tid & 63, w = tid >> 6;           // w in 0..7
    int col = lane & 15, q = lane >> 4;
    int arow = (w & 3)*16 + col;                 // xT row for MFMA1 A-frag
    int akey = (arow >> 1) & 31;
    int ntbase = (w >> 2) ? 7 : 0;               // node-tile split: 7 / 6
    int ntcnt  = (w >> 2) ? 6 : 7;

    // ---- MFMA1 with As prefetch pipeline ----
    f32x4 acc1[7];
    #pragma unroll
    for (int t = 0; t < 7; ++t) acc1[t] = (f32x4){0.f,0.f,0.f,0.f};
    unsigned int pf[7];
    for (int step = 0; step < 7; ++step) {
        if (step < 6) {
            int kb = (step + 1) * 16;            // dword offset into Ab row
            #pragma unroll
            for (int it = 0; it < 7; ++it) {
                int idx = tid + it*512;
                if (idx < NPAD*16) pf[it] = Ab32[(idx>>4)*112 + kb + (idx&15)];
            }
        }
        int cb = step*4;                          // chunk base = k0>>3
        bf16x8 a = *(const bf16x8*)(&smem[arow*XSW + ((((cb + q) ^ akey) & 31)<<3)]);
        #pragma unroll
        for (int t = 0; t < 7; ++t) {
            if (t < ntcnt) {
                int nt = ntbase + t;
                bf16x8 bb = *(const bf16x8*)(&smem[ASOFF + (nt*16 + col)*ASP + q*8]);
                acc1[t] = __builtin_amdgcn_mfma_f32_16x16x32_bf16(a, bb, acc1[t], 0, 0, 0);
            }
        }
        __syncthreads();                          // As consumed by all waves
        if (step < 6) {
            #pragma unroll
            for (int it = 0; it < 7; ++it) {
                int idx = tid + it*512;
                if (idx < NPAD*16) sm32[ASOFF32 + (idx>>4)*20 + (idx&15)] = pf[it];
            }
        }
        __syncthreads();                          // As slice ready
    }

    // ---- hoist residual x[node][h'] from xT before overwrite ----
    unsigned long long res[2][4];
    #pragma unroll
    for (int j = 0; j < 2; ++j) {
        int mt = w + 8*j;
        if (mt < 13) {
            #pragma unroll
            for (int nt2 = 0; nt2 < 4; ++nt2) {
                int rr = nt2*16 + col;            // xT row (h')
                int k  = mt*16 + q*4;             // node col
                res[j][nt2] = *(const unsigned long long*)
                    (&smem[rr*XSW + ((((k>>3) ^ ((rr>>1)&31)) & 31)<<3) + (k&7)]);
            }
        }
    }
    __syncthreads();
    // ---- write z (union over xT region) + stage gcn_W into As region ----
    #pragma unroll
    for (int t = 0; t < 7; ++t) {
        if (t < ntcnt) {
            int nt = ntbase + t;
            unsigned long long pk =
                  (unsigned long long)f2bf(acc1[t][0])
                | ((unsigned long long)f2bf(acc1[t][1]) << 16)
                | ((unsigned long long)f2bf(acc1[t][2]) << 32)
                | ((unsigned long long)f2bf(acc1[t][3]) << 48);
            *(unsigned long long*)(&smem[(nt*16 + col)*ZP + (w&3)*16 + q*4]) = pk;
        }
    }
    for (int i = tid; i < 64*32; i += 512) {
        int n2 = i >> 5, kdw = i & 31;
        sm32[ASOFF32 + n2*36 + kdw] = gW32[n2*32 + kdw];
    }
    __syncthreads();

    // ---- MFMA2 + LN; results written back into z region (own rows) ----
    float gbv[4], lwv[4], lbv[4];
    #pragma unroll
    for (int nt2 = 0; nt2 < 4; ++nt2) {
        int h = nt2*16 + col;
        gbv[nt2] = gb[h]; lwv[nt2] = lnw[h]; lbv[nt2] = lnb[h];
    }
    #pragma unroll
    for (int j = 0; j < 2; ++j) {
        int mt = w + 8*j;
        if (mt >= 13) break;                      // wave-uniform
        f32x4 acc2[4];
        #pragma unroll
        for (int nt2 = 0; nt2 < 4; ++nt2) acc2[nt2] = (f32x4){0.f,0.f,0.f,0.f};
        #pragma unroll
        for (int k0 = 0; k0 < HH; k0 += 32) {
            bf16x8 a = *(const bf16x8*)(&smem[(mt*16 + col)*ZP + k0 + q*8]);
            #pragma unroll
            for (int nt2 = 0; nt2 < 4; ++nt2) {
                bf16x8 bw = *(const bf16x8*)(&smem[ASOFF + (nt2*16 + col)*GWP + k0 + q*8]);
                acc2[nt2] = __builtin_amdgcn_mfma_f32_16x16x32_bf16(a, bw, acc2[nt2], 0, 0, 0);
            }
        }
        float v[4][4];
        float sv[4] = {0.f,0.f,0.f,0.f}, sq[4] = {0.f,0.f,0.f,0.f};
        #pragma unroll
        for (int nt2 = 0; nt2 < 4; ++nt2) {
            unsigned long long rr = res[j][nt2];
            #pragma unroll
            for (int r = 0; r < 4; ++r) {
                float t = acc2[nt2][r] + bf2f((unsigned short)(rr >> (16*r))) + gbv[nt2];
                v[nt2][r] = t; sv[r] += t; sq[r] += t*t;
            }
        }
        #pragma unroll
        for (int r = 0; r < 4; ++r) {
            #pragma unroll
            for (int off = 1; off < 16; off <<= 1) {
                sv[r] += __shfl_xor(sv[r], off, 64);
                sq[r] += __shfl_xor(sq[r], off, 64);
            }
        }
        #pragma unroll
        for (int r = 0; r < 4; ++r) {
            float mu  = sv[r] * (1.f/64.f);
            float var = sq[r] * (1.f/64.f) - mu*mu;
            float rstd = 1.f / sqrtf(var + EPSF);
            int node = mt*16 + q*4 + r;
            #pragma unroll
            for (int nt2 = 0; nt2 < 4; ++nt2) {
                float o = (v[nt2][r] - mu) * rstd * lwv[nt2] + lbv[nt2];
                smem[node*ZP + nt2*16 + col] = f2bf(o);
            }
        }
    }
    __syncthreads();
    // ---- coalesced write-out: full 128 B line per node (b128 chunks) ----
    for (int i = tid; i < NN*8; i += 512) {
        int node = i >> 3, c16 = i & 7;
        uint4 vv = *(const uint4*)(&smem[node*ZP + c16*8]);
        *(uint4*)(xbase + (size_t)node*SH + c16*8) = vv;
    }
}

// ---------------------------------------------------------------------------
// Head futr+bias: out[row,p] = c0[p] + xfut[row,:192] @ C1   (plain writes,
// runs BEFORE k_head_mfma which atomically accumulates the hist GEMM)
// ---------------------------------------------------------------------------
__global__ __launch_bounds__(192) void k_head_futr(const float* __restrict__ xfut,
        const float* __restrict__ C1, const float* __restrict__ c0,
        float* __restrict__ out) {
    __shared__ float C1l[192*PP];   // 36.8 KB
    __shared__ float xfl[4*192];    // 3 KB
    int tid = threadIdx.x;
    int r0 = blockIdx.x * 4;
    for (int i = tid; i < 192*PP; i += 192) C1l[i] = C1[i];
    for (int i = tid; i < 4*192; i += 192) xfl[i] = xfut[(size_t)r0*192 + i];
    __syncthreads();
    int p = tid % PP, rr = tid / PP;
    float acc = c0[p];
    #pragma unroll 8
    for (int j = 0; j < 192; ++j) acc += xfl[rr*192 + j] * C1l[j*PP + p];
    out[(size_t)(r0 + rr)*PP + p] = acc;
}

// ---------------------------------------------------------------------------
// Head hist GEMM (bf16 MFMA): out[row,p] += X[row,:12288] @ hWT^T
// A-op = X rows straight from global; B-op = hWT (L2-hot). Split-K x8.
// ---------------------------------------------------------------------------
#define KSL 1536
__global__ __launch_bounds__(256) void k_head_mfma(const unsigned short* __restrict__ X,
        const unsigned short* __restrict__ hWT, float* __restrict__ out) {
    int tid = threadIdx.x;
    int lane = tid & 63, w = tid >> 6;
    int col = lane & 15, q = lane >> 4;
    int m0 = blockIdx.x*64 + w*16;
    int k0 = blockIdx.y*KSL;
    const unsigned short* xp = X + (size_t)(m0 + col)*SH + k0 + q*8;
    const unsigned short* wp = hWT + (size_t)col*SH + k0 + q*8;
    f32x4 acc[3];
    #pragma unroll
    for (int nt = 0; nt < 3; ++nt) acc[nt] = (f32x4){0.f,0.f,0.f,0.f};
    #pragma unroll 4
    for (int kk = 0; kk < KSL; kk += 32) {
        bf16x8 a = *(const bf16x8*)(xp + kk);
        #pragma unroll
        for (int nt = 0; nt < 3; ++nt) {
            bf16x8 b = *(const bf16x8*)(wp + (size_t)nt*16*SH + kk);
            acc[nt] = __builtin_amdgcn_mfma_f32_16x16x32_bf16(a, b, acc[nt], 0, 0, 0);
        }
    }
    int orow = m0 + q*4;
    #pragma unroll
    for (int nt = 0; nt < 3; ++nt)
        #pragma unroll
        for (int r = 0; r < 4; ++r)
            atomicAdd(&out[(size_t)(orow + r)*PP + nt*16 + col], acc[nt][r]);
}

// ---------------------------------------------------------------------------
extern "C" void kernel_launch(void* const* d_in, const int* in_sizes, int n_in,
                              void* d_out, int out_size, void* d_ws, size_t ws_size,
                              hipStream_t stream) {
    const float* x     = (const float*)d_in[0];
    const float* xfut  = (const float*)d_in[1];
    const float* adj   = (const float*)d_in[2];
    const float* emb   = (const float*)d_in[3];
    const float* alpha = (const float*)d_in[4];
    const float* inw   = (const float*)d_in[5];
    const float* inb   = (const float*)d_in[6];
    const float* pW    = (const float*)d_in[7];
    const float* pb    = (const float*)d_in[8];
    const float* tW    = (const float*)d_in[9];
    const float* tb    = (const float*)d_in[10];
    const float* gW    = (const float*)d_in[11];
    const float* gb    = (const float*)d_in[12];
    const float* lnw   = (const float*)d_in[13];
    const float* lnb   = (const float*)d_in[14];
    const float* fW    = (const float*)d_in[15];
    const float* fb    = (const float*)d_in[16];
    const float* hW    = (const float*)d_in[17];
    const float* hb    = (const float*)d_in[18];
    float* out = (float*)d_out;

    // Workspace layout (~160 MB): bufX 157.3MB + adjacency/weights ~1.6MB
    unsigned short* bufX = (unsigned short*)d_ws;
    float* Amat = (float*)(bufX + XSZ);
    float* Araw = Amat + NN*NN;
    float* dvec = Araw + NN*NN;
    unsigned short* tWb = (unsigned short*)(dvec + NN);
    unsigned short* Ab  = tWb + NBLK*SS*SS;
    unsigned short* gWT = Ab + NPAD*KPAD;
    unsigned short* hWT = gWT + NBLK*HH*HH;
    float* C1 = (float*)(hWT + (size_t)PP*SH);
    float* c0 = C1 + 192*PP;

    k_adj_row<<<NN, 64, 0, stream>>>(emb, adj, alpha, Araw, dvec);
    k_adj_scale<<<NN, 256, 0, stream>>>(Araw, dvec, Amat);
    k_prep<<<(NBLK*SS*SS + 255)/256, 256, 0, stream>>>(tW, gW, Amat, tWb, Ab, gWT);
    k_prep2<<<((size_t)PP*SH + 255)/256, 256, 0, stream>>>(hW, fW, fb, hb, hWT, C1, c0);

    // fused stage0 + temporal block 0
    k_stage0_temporal<<<ROWS, 256, 0, stream>>>(x, inw, inb, pW, pb, emb, bufX, tWb, tb);
    k_spatial_fused<<<dim3(SS, BB), 512, 0, stream>>>(bufX, Ab, gWT, gb, lnw, lnb);
    for (int i = 1; i < NBLK; ++i) {
        k_temporal_mfma<<<ROWS, 256, 0, stream>>>(bufX, tWb + (size_t)i*SS*SS, tb + i*SS);
        k_spatial_fused<<<dim3(SS, BB), 512, 0, stream>>>(bufX, Ab, gWT + (size_t)i*HH*HH,
                                                          gb + i*HH, lnw + i*HH, lnb + i*HH);
    }
    k_head_futr<<<ROWS/4, 192, 0, stream>>>(xfut, C1, c0, out);
    k_head_mfma<<<dim3(ROWS/64, 8), 256, 0, stream>>>(bufX, hWT, out);
}